// Round 14
// baseline (647.180 us; speedup 1.0000x reference)
//
#include <hip/hip_runtime.h>
#include <hip/hip_cooperative_groups.h>
#include <cstdint>

namespace cg = cooperative_groups;

#define MUL0 16
#define MUL1 8
#define NRBF 8
#define HID 64
#define WNUM 576
#define CUTOFF 5.0f
#define EPSF 1e-8f

#define INV_SQRT3 0.57735026918962576f
#define A_PATH    0.20412414523193154f   /* 1/sqrt(24) */
#define Q16       0.25f                  /* 1/sqrt(16) */
#define Q8        0.35355339059327373f   /* 1/sqrt(8)  */
#define PI_OVER_CUT 0.62831853071795865f /* pi/5 */

typedef _Float16 f16;
typedef _Float16 f16x8 __attribute__((ext_vector_type(8)));
typedef float f32x4 __attribute__((ext_vector_type(4)));

#define MFMA16(a, b, cc) __builtin_amdgcn_mfma_f32_16x16x32_f16(a, b, cc, 0, 0, 0)

__device__ __forceinline__ float sigm(float x) { return 1.0f / (1.0f + __expf(-x)); }

typedef __attribute__((address_space(1))) const unsigned char* gptr_t;
typedef __attribute__((address_space(3))) unsigned char* lptr_t;

__device__ __forceinline__ void stage16(const void* g, void* l) {
  __builtin_amdgcn_global_load_lds((gptr_t)g, (lptr_t)l, 16, 0, 0);
}

// ==================== device helpers (shared by mega + fallback) ============

__device__ __forceinline__ void pre_body(
    int gid, const float* __restrict__ x, float* __restrict__ xnorm,
    float* __restrict__ agg0, float* __restrict__ agg1,
    float* __restrict__ normb, const float* __restrict__ w_r2,
    f16* __restrict__ W2T, int N) {
  if (gid < HID * WNUM) {
    int n = gid >> 6, k = gid & 63;
    int jt = n >> 4, cc = n & 15;
    int h = k >> 3, e = k & 7;
    int dst = jt * 1024 + cc * 64 + ((h ^ (cc & 7)) << 3) + e;
    W2T[dst] = (f16)w_r2[k * WNUM + n];
  }
  if (gid < N) {
    long long n = gid;
    const float4* xr = (const float4*)(x + n * 40);
    float4 vv[10];
#pragma unroll
    for (int i = 0; i < 10; i++) vv[i] = xr[i];
    float* f = (float*)vv;
    float ss = 0.f, vs = 0.f;
#pragma unroll
    for (int i = 0; i < 16; i++) ss += f[i] * f[i];
#pragma unroll
    for (int i = 16; i < 40; i++) vs += f[i] * f[i];
    float sr = rsqrtf(ss * (1.0f / 16.0f) + EPSF);
    float vr = rsqrtf(vs * (1.0f / 8.0f) + EPSF);
#pragma unroll
    for (int i = 0; i < 16; i++) f[i] *= sr;
#pragma unroll
    for (int i = 16; i < 40; i++) f[i] *= vr;
    float4* o = (float4*)(xnorm + n * 40);
#pragma unroll
    for (int i = 0; i < 10; i++) o[i] = vv[i];
    float4 z = {0.f, 0.f, 0.f, 0.f};
    float4* pa0 = (float4*)(agg0 + n * 16);
#pragma unroll
    for (int i = 0; i < 4; i++) pa0[i] = z;
    float4* pa1 = (float4*)(agg1 + n * 24);
#pragma unroll
    for (int i = 0; i < 6; i++) pa1[i] = z;
    normb[n] = 0.f;
  }
}

// edge tile body: processes 128 edges starting at vb*128 using block smem.
// R10/R11-verified structure: DMA-staged double-buffered W2T ring, 9 chunks.
__device__ __forceinline__ void edge_tile(
    char* smem, int vb, const float* __restrict__ xnorm,
    const int* __restrict__ esrc, const int* __restrict__ edst,
    const float* __restrict__ sh, const float* __restrict__ rbf,
    const float* __restrict__ elen,
    const float* __restrict__ w_r1, const float* __restrict__ b_r1,
    const float* __restrict__ w_g1, const float* __restrict__ b_g1,
    const float* __restrict__ w_g2, const float* __restrict__ b_g2,
    const float* __restrict__ b_r2, const f16* __restrict__ W2T,
    float* __restrict__ agg0, float* __restrict__ agg1,
    float* __restrict__ normb, int E) {
  f16   (*s_H)[32][72]  = (f16(*)[32][72])(smem);             // 18432 (dead in B)
  float (*s_sn)[32][20] = (float(*)[32][20])(smem + 18432);   // 10240
  float (*s_v)[32][26]  = (float(*)[32][26])(smem + 28672);   // 13312
  float (*s_a1)[32][10] = (float(*)[32][10])(smem + 41984);   //  5120
  float (*s_sh)[32][4]  = (float(*)[32][4])(smem + 47104);    //  2048
  float (*s_rbf)[32][8] = (float(*)[32][8])(smem + 49152);    //  4096 (dead in B)
  float* s_bias = (float*)(smem + 49152);                     // aliases s_rbf

  const int t = threadIdx.x;
  const int w = t >> 6;
  const int lane = t & 63;
  const long long eb = (long long)vb * 128 + w * 32;

  // ---- A0: direct coalesced edge loads ----
  int dstv = 0, srcv = 0;
  float lenv = 1e9f;
  if (lane < 32) {
    long long g2 = eb + lane;
    float4 shv = {0.f, 0.f, 0.f, 0.f};
    if (g2 < E) {
      srcv = esrc[g2];
      dstv = edst[g2];
      lenv = elen[g2];
      shv = *(const float4*)&sh[g2 * 4];
    }
    *(float4*)&s_sh[w][lane][0] = shv;
  }
  {
    int e = lane >> 1, half = lane & 1;
    long long ge2 = eb + e;
    float4 rv4 = {0.f, 0.f, 0.f, 0.f};
    if (ge2 < E) rv4 = *(const float4*)&rbf[ge2 * 8 + half * 4];
    *(float4*)&s_rbf[w][e][half * 4] = rv4;
  }
  __syncthreads();

  // ---- A1: gather xnorm + transform ----
  {
    const int ge_l = lane >> 2;
    const int part = lane & 3;
#pragma unroll
    for (int g = 0; g < 2; g++) {
      int e = g * 16 + ge_l;
      int srcn = __shfl(srcv, e);
      const float* xr = xnorm + (long long)srcn * 40;
      if (part < 2) {
        float4 aLo = *(const float4*)(xr + part * 8);
        float4 aHi = *(const float4*)(xr + part * 8 + 4);
        *(float4*)&s_sn[w][e][part * 8] = aLo;
        *(float4*)&s_sn[w][e][part * 8 + 4] = aHi;
      } else {
        const int i0 = (part - 2) * 4;
        const float* vp = xr + 16 + i0 * 3;
        float4 v0 = *(const float4*)(vp);
        float4 v1 = *(const float4*)(vp + 4);
        float4 v2 = *(const float4*)(vp + 8);
        *(float4*)&s_v[w][e][i0 * 3] = v0;
        *(float4*)&s_v[w][e][i0 * 3 + 4] = v1;
        *(float4*)&s_v[w][e][i0 * 3 + 8] = v2;
        float4 shq = *(const float4*)&s_sh[w][e][0];
        float s1x = shq.y, s1y = shq.z, s1z = shq.w;
        s_a1[w][e][i0]     = INV_SQRT3 * (v0.x * s1x + v0.y * s1y + v0.z * s1z);
        s_a1[w][e][i0 + 1] = INV_SQRT3 * (v0.w * s1x + v1.x * s1y + v1.y * s1z);
        s_a1[w][e][i0 + 2] = INV_SQRT3 * (v1.z * s1x + v1.w * s1y + v2.x * s1z);
        s_a1[w][e][i0 + 3] = INV_SQRT3 * (v2.y * s1x + v2.z * s1y + v2.w * s1z);
      }
    }
  }

  // ---- A2: hidden layer H ----
  {
    float wr[8];
#pragma unroll
    for (int r = 0; r < 8; r++) wr[r] = w_r1[r * HID + lane];
    float bh = b_r1[lane];
#pragma unroll 4
    for (int u = 0; u < 32; u++) {
      float4 ra = *(const float4*)&s_rbf[w][u][0];
      float4 rb2 = *(const float4*)&s_rbf[w][u][4];
      float acc = bh + ra.x * wr[0] + ra.y * wr[1] + ra.z * wr[2] + ra.w * wr[3]
                     + rb2.x * wr[4] + rb2.y * wr[5] + rb2.z * wr[6] + rb2.w * wr[7];
      s_H[w][u][lane] = (f16)(acc * sigm(acc));
    }
  }

  // ---- A3: gate MLP ----
  float ewv = 0.f;
  {
    const int eg = lane & 31;
    const int hf = lane >> 5;
    float4 ga = *(const float4*)&s_rbf[w][eg][0];
    float4 gb = *(const float4*)&s_rbf[w][eg][4];
    float rv[8] = {ga.x, ga.y, ga.z, ga.w, gb.x, gb.y, gb.z, gb.w};
    float accp = 0.f;
#pragma unroll
    for (int ch = 0; ch < 2; ch++) {
      const int base = hf * 32 + ch * 16;
      float ttv[16];
      {
        const float4 b0 = *(const float4*)&b_g1[base];
        const float4 b1 = *(const float4*)&b_g1[base + 4];
        const float4 b2 = *(const float4*)&b_g1[base + 8];
        const float4 b3 = *(const float4*)&b_g1[base + 12];
        ttv[0] = b0.x; ttv[1] = b0.y; ttv[2] = b0.z; ttv[3] = b0.w;
        ttv[4] = b1.x; ttv[5] = b1.y; ttv[6] = b1.z; ttv[7] = b1.w;
        ttv[8] = b2.x; ttv[9] = b2.y; ttv[10] = b2.z; ttv[11] = b2.w;
        ttv[12] = b3.x; ttv[13] = b3.y; ttv[14] = b3.z; ttv[15] = b3.w;
      }
#pragma unroll
      for (int r = 0; r < 8; r++) {
        const float* wg = w_g1 + r * HID + base;
        float4 w0 = *(const float4*)(wg);
        float4 w1 = *(const float4*)(wg + 4);
        float4 w2 = *(const float4*)(wg + 8);
        float4 w3 = *(const float4*)(wg + 12);
        float rr = rv[r];
        ttv[0] += rr * w0.x; ttv[1] += rr * w0.y; ttv[2] += rr * w0.z; ttv[3] += rr * w0.w;
        ttv[4] += rr * w1.x; ttv[5] += rr * w1.y; ttv[6] += rr * w1.z; ttv[7] += rr * w1.w;
        ttv[8] += rr * w2.x; ttv[9] += rr * w2.y; ttv[10] += rr * w2.z; ttv[11] += rr * w2.w;
        ttv[12] += rr * w3.x; ttv[13] += rr * w3.y; ttv[14] += rr * w3.z; ttv[15] += rr * w3.w;
      }
      const float4 g0 = *(const float4*)&w_g2[base];
      const float4 g1 = *(const float4*)&w_g2[base + 4];
      const float4 g2 = *(const float4*)&w_g2[base + 8];
      const float4 g3 = *(const float4*)&w_g2[base + 12];
      float gw[16] = {g0.x, g0.y, g0.z, g0.w, g1.x, g1.y, g1.z, g1.w,
                      g2.x, g2.y, g2.z, g2.w, g3.x, g3.y, g3.z, g3.w};
#pragma unroll
      for (int k = 0; k < 16; k++) accp += ttv[k] * sigm(ttv[k]) * gw[k];
    }
    accp += __shfl_xor(accp, 32);
    if (lane < 32) {
      long long g2e = eb + lane;
      if (g2e < E) {
        float cw = (lenv < CUTOFF) ? 0.5f * (__cosf(PI_OVER_CUT * lenv) + 1.0f) : 0.f;
        ewv = cw * sigm(accp + b_g2[0]);
      }
    }
  }
  __syncthreads();

  // ---- B prologue ----
  const int quad = lane >> 4;
  const int c = lane & 15;

  const f16x8 af00 = *(const f16x8*)&s_H[w][c][quad * 8];
  const f16x8 af01 = *(const f16x8*)&s_H[w][c][32 + quad * 8];
  const f16x8 af10 = *(const f16x8*)&s_H[w][16 + c][quad * 8];
  const f16x8 af11 = *(const f16x8*)&s_H[w][16 + c][32 + quad * 8];
  for (int i = t; i < WNUM; i += 256) s_bias[i] = b_r2[i];
  __syncthreads();

  char* ring = smem;
  const char* W2Tc = (const char*)W2T;
  const int lofs = w * 1024;
  const int gofs = w * 1024 + lane * 16;

  stage16(W2Tc + gofs, ring + lofs);
  stage16(W2Tc + 4096 + gofs, ring + 4096 + lofs);

  const int rd0 = c * 128 + ((quad ^ (c & 7)) << 4);
  const int rd1 = c * 128 + (((quad + 4) ^ (c & 7)) << 4);

  float p1[2][4] = {{0.f}}, p2[2][4] = {{0.f}}, t3[2][4] = {{0.f}};
  float mx[2][4] = {{0.f}}, my[2][4] = {{0.f}}, mz[2][4] = {{0.f}};

#pragma unroll 1
  for (int ch = 0; ch < 4; ch++) {
    __syncthreads();
    stage16(W2Tc + (ch + 1) * 8192 + gofs, ring + ((ch + 1) & 1) * 8192 + lofs);
    stage16(W2Tc + (ch + 1) * 8192 + 4096 + gofs,
            ring + ((ch + 1) & 1) * 8192 + 4096 + lofs);
    const char* bb = ring + (ch & 1) * 8192;
#pragma unroll
    for (int q = 0; q < 4; q++) {
      const int jt = ch * 4 + q;
      const char* tb = bb + q * 2048;
      f16x8 b0 = *(const f16x8*)(tb + rd0);
      f16x8 b1 = *(const f16x8*)(tb + rd1);
      float bias = s_bias[jt * 16 + c];
      f32x4 C0 = {0.f, 0.f, 0.f, 0.f};
      C0 = MFMA16(af00, b0, C0); C0 = MFMA16(af01, b1, C0);
      f32x4 C1 = {0.f, 0.f, 0.f, 0.f};
      C1 = MFMA16(af10, b0, C1); C1 = MFMA16(af11, b1, C1);
#pragma unroll
      for (int r = 0; r < 4; r++) {
        p1[0][r] += s_sn[w][quad * 4 + r][jt] * (C0[r] + bias);
        p1[1][r] += s_sn[w][16 + quad * 4 + r][jt] * (C1[r] + bias);
      }
    }
  }
#pragma unroll 1
  for (int ch = 4; ch < 6; ch++) {
    __syncthreads();
    stage16(W2Tc + (ch + 1) * 8192 + gofs, ring + ((ch + 1) & 1) * 8192 + lofs);
    stage16(W2Tc + (ch + 1) * 8192 + 4096 + gofs,
            ring + ((ch + 1) & 1) * 8192 + 4096 + lofs);
    const char* bb = ring + (ch & 1) * 8192;
#pragma unroll
    for (int q = 0; q < 4; q++) {
      const int jt = ch * 4 + q;
      const char* tb = bb + q * 2048;
      f16x8 b0 = *(const f16x8*)(tb + rd0);
      f16x8 b1 = *(const f16x8*)(tb + rd1);
      float bias = s_bias[jt * 16 + c];
      f32x4 C0 = {0.f, 0.f, 0.f, 0.f};
      C0 = MFMA16(af00, b0, C0); C0 = MFMA16(af01, b1, C0);
      f32x4 C1 = {0.f, 0.f, 0.f, 0.f};
      C1 = MFMA16(af10, b0, C1); C1 = MFMA16(af11, b1, C1);
      const int i = jt - 16;
#pragma unroll
      for (int r = 0; r < 4; r++) {
        p2[0][r] += s_a1[w][quad * 4 + r][i] * (C0[r] + bias);
        p2[1][r] += s_a1[w][16 + quad * 4 + r][i] * (C1[r] + bias);
      }
    }
  }
#pragma unroll 1
  for (int ch = 6; ch < 8; ch++) {
    __syncthreads();
    stage16(W2Tc + (ch + 1) * 8192 + gofs, ring + ((ch + 1) & 1) * 8192 + lofs);
    stage16(W2Tc + (ch + 1) * 8192 + 4096 + gofs,
            ring + ((ch + 1) & 1) * 8192 + 4096 + lofs);
    const char* bb = ring + (ch & 1) * 8192;
#pragma unroll
    for (int q = 0; q < 4; q++) {
      const int jt = ch * 4 + q;
      const char* tb = bb + q * 2048;
      f16x8 b0 = *(const f16x8*)(tb + rd0);
      f16x8 b1 = *(const f16x8*)(tb + rd1);
      float bias = s_bias[jt * 16 + c];
      f32x4 C0 = {0.f, 0.f, 0.f, 0.f};
      C0 = MFMA16(af00, b0, C0); C0 = MFMA16(af01, b1, C0);
      f32x4 C1 = {0.f, 0.f, 0.f, 0.f};
      C1 = MFMA16(af10, b0, C1); C1 = MFMA16(af11, b1, C1);
      const int i = (jt - 24) * 2 + (c >> 3);
#pragma unroll
      for (int r = 0; r < 4; r++) {
        t3[0][r] += s_sn[w][quad * 4 + r][i] * (C0[r] + bias);
        t3[1][r] += s_sn[w][16 + quad * 4 + r][i] * (C1[r] + bias);
      }
    }
  }
  {
    __syncthreads();
    const char* bb = ring + 8192;   // chunk 8 is odd slot
#pragma unroll
    for (int q = 0; q < 4; q++) {
      const int jt = 32 + q;
      const char* tb = bb + q * 2048;
      f16x8 b0 = *(const f16x8*)(tb + rd0);
      f16x8 b1 = *(const f16x8*)(tb + rd1);
      float bias = s_bias[jt * 16 + c];
      f32x4 C0 = {0.f, 0.f, 0.f, 0.f};
      C0 = MFMA16(af00, b0, C0); C0 = MFMA16(af01, b1, C0);
      f32x4 C1 = {0.f, 0.f, 0.f, 0.f};
      C1 = MFMA16(af10, b0, C1); C1 = MFMA16(af11, b1, C1);
      const int i = q * 2 + (c >> 3);
#pragma unroll
      for (int r = 0; r < 4; r++) {
        float wv0 = C0[r] + bias;
        float wv1 = C1[r] + bias;
        mx[0][r] += s_v[w][quad * 4 + r][3 * i] * wv0;
        my[0][r] += s_v[w][quad * 4 + r][3 * i + 1] * wv0;
        mz[0][r] += s_v[w][quad * 4 + r][3 * i + 2] * wv0;
        mx[1][r] += s_v[w][16 + quad * 4 + r][3 * i] * wv1;
        my[1][r] += s_v[w][16 + quad * 4 + r][3 * i + 1] * wv1;
        mz[1][r] += s_v[w][16 + quad * 4 + r][3 * i + 2] * wv1;
      }
    }
  }

#pragma unroll
  for (int g = 0; g < 2; g++)
#pragma unroll
    for (int r = 0; r < 4; r++) {
      t3[g][r] += __shfl_xor(t3[g][r], 8);
      mx[g][r] += __shfl_xor(mx[g][r], 8);
      my[g][r] += __shfl_xor(my[g][r], 8);
      mz[g][r] += __shfl_xor(mz[g][r], 8);
    }

#pragma unroll
  for (int g = 0; g < 2; g++) {
    const int e0g = g * 16 + quad * 4;
    int cur = __shfl(dstv, e0g);
    float acc0 = 0.f, a1x = 0.f, a1y = 0.f, a1z = 0.f, nacc = 0.f;
#pragma unroll
    for (int r = 0; r < 4; r++) {
      const int e = e0g + r;
      const int dst = __shfl(dstv, e);
      const float ew = __shfl(ewv, e);
      if (dst != cur) {
        atomicAdd(&agg0[(long long)cur * 16 + c], acc0);
        if (c < 8) {
          long long b = (long long)cur * 24 + (long long)c * 3;
          atomicAdd(&agg1[b], a1x);
          atomicAdd(&agg1[b + 1], a1y);
          atomicAdd(&agg1[b + 2], a1z);
        } else if (c == 8) {
          atomicAdd(&normb[cur], nacc);
        }
        acc0 = a1x = a1y = a1z = nacc = 0.f;
        cur = dst;
      }
      float sc2 = A_PATH * ew;
      float sh0 = s_sh[w][e][0];
      acc0 += (sh0 * p1[g][r] + p2[g][r]) * sc2;
      if (c < 8) {
        float t3v = t3[g][r] * sc2;
        float scs = sc2 * sh0;
        a1x += t3v * s_sh[w][e][1] + mx[g][r] * scs;
        a1y += t3v * s_sh[w][e][2] + my[g][r] * scs;
        a1z += t3v * s_sh[w][e][3] + mz[g][r] * scs;
      } else if (c == 8) {
        nacc += ew;
      }
    }
    atomicAdd(&agg0[(long long)cur * 16 + c], acc0);
    if (c < 8) {
      long long b = (long long)cur * 24 + (long long)c * 3;
      atomicAdd(&agg1[b], a1x);
      atomicAdd(&agg1[b + 1], a1y);
      atomicAdd(&agg1[b + 2], a1z);
    } else if (c == 8) {
      atomicAdd(&normb[cur], nacc);
    }
  }
}

// node body for one n, weights already staged in sW* LDS views.
__device__ __forceinline__ void node_body(
    long long n, const float* __restrict__ x, const float* __restrict__ xnorm,
    const float* __restrict__ agg0, const float* __restrict__ agg1,
    const float* __restrict__ normb, const float* sWms, const float* sWmv,
    const float* sWus, const float* sWuv, const float* sWss,
    const float* sWsv, float rs, float* __restrict__ out) {
  float inv = 1.0f / fmaxf(normb[n], EPSF);
  float4 a04[4], a14[6];
  {
    const float4* p = (const float4*)(agg0 + n * 16);
#pragma unroll
    for (int i = 0; i < 4; i++) a04[i] = p[i];
    const float4* q = (const float4*)(agg1 + n * 24);
#pragma unroll
    for (int i = 0; i < 6; i++) a14[i] = q[i];
  }
  float* a0 = (float*)a04;
  float* a1 = (float*)a14;
#pragma unroll
  for (int i = 0; i < 16; i++) a0[i] *= inv;
#pragma unroll
  for (int i = 0; i < 24; i++) a1[i] *= inv;

  float scal[16], gate[8];
#pragma unroll
  for (int jj = 0; jj < 24; jj++) {
    float acc = 0.f;
#pragma unroll
    for (int i = 0; i < 16; i++) acc += a0[i] * sWms[i * 24 + jj];
    acc *= Q16;
    if (jj < 16) scal[jj] = acc * sigm(acc);
    else gate[jj - 16] = sigm(acc);
  }
  float vg[24];
#pragma unroll
  for (int j = 0; j < 8; j++) {
    float g = gate[j];
#pragma unroll
    for (int cc = 0; cc < 3; cc++) {
      float acc = 0.f;
#pragma unroll
      for (int i = 0; i < 8; i++) acc += a1[i * 3 + cc] * sWmv[i * 8 + j];
      vg[j * 3 + cc] = acc * Q8 * g;
    }
  }
  float4 xn4[10], xo4[10];
  {
    const float4* p = (const float4*)(xnorm + n * 40);
    const float4* q = (const float4*)(x + n * 40);
#pragma unroll
    for (int i = 0; i < 10; i++) { xn4[i] = p[i]; xo4[i] = q[i]; }
  }
  const float* xn = (const float*)xn4;
  const float* xo = (const float*)xo4;

  float4 ob[10];
  float* ov = (float*)ob;
#pragma unroll
  for (int j = 0; j < 16; j++) {
    float acc = 0.f, acc2 = 0.f;
#pragma unroll
    for (int i = 0; i < 16; i++) {
      acc += scal[i] * sWus[i * 16 + j];
      acc2 += xn[i] * sWss[i * 16 + j];
    }
    ov[j] = xo[j] + rs * ((acc + acc2) * Q16);
  }
#pragma unroll
  for (int j = 0; j < 8; j++) {
#pragma unroll
    for (int cc = 0; cc < 3; cc++) {
      float acc = 0.f;
#pragma unroll
      for (int i = 0; i < 8; i++)
        acc += vg[i * 3 + cc] * sWuv[i * 8 + j] + xn[16 + i * 3 + cc] * sWsv[i * 8 + j];
      ov[16 + j * 3 + cc] = xo[16 + j * 3 + cc] + rs * (acc * Q8);
    }
  }
  float4* po = (float4*)(out + n * 40);
#pragma unroll
  for (int i = 0; i < 10; i++) po[i] = ob[i];
}

// ==================== cooperative mega-kernel ====================
extern "C" __global__ __launch_bounds__(256, 3) void k_mega(
    const float* x, const int* esrc, const int* edst, const float* sh,
    const float* rbf, const float* elen, const float* w_r1,
    const float* b_r1, const float* w_g1, const float* b_g1,
    const float* w_g2, const float* b_g2, const float* b_r2,
    const float* w_r2, const float* Wm_s, const float* Wm_v,
    const float* Wu_s, const float* Wu_v, const float* Ws_s,
    const float* Ws_v, const float* res_scale_p, float* xnorm,
    float* agg0, float* agg1, float* normb, f16* W2T, float* out,
    int N, int E, int nbPre, int nblkE, int nbN) {
  __shared__ __align__(16) char smem[53248];
  cg::grid_group grid = cg::this_grid();
  const int t = threadIdx.x;

  // ---- PHASE 1: pre (W2T transpose + xnorm + agg zero), grid-strided ----
  for (int vb = blockIdx.x; vb < nbPre; vb += gridDim.x)
    pre_body(vb * 256 + t, x, xnorm, agg0, agg1, normb, w_r2, W2T, N);
  __threadfence();
  grid.sync();

  // ---- PHASE 2: edges, grid-strided over 128-edge tiles ----
  for (int vb = blockIdx.x; vb < nblkE; vb += gridDim.x) {
    __syncthreads();   // protect smem reuse across tile iterations
    edge_tile(smem, vb, xnorm, esrc, edst, sh, rbf, elen, w_r1, b_r1, w_g1,
              b_g1, w_g2, b_g2, b_r2, W2T, agg0, agg1, normb, E);
  }
  __threadfence();
  grid.sync();

  // ---- PHASE 3: node, grid-strided, weights staged in aliased LDS ----
  {
    float* sW = (float*)smem;
    float* sWms = sW;            // 384
    float* sWmv = sW + 384;      // 64
    float* sWus = sW + 448;      // 256
    float* sWuv = sW + 704;      // 64
    float* sWss = sW + 768;      // 256
    float* sWsv = sW + 1024;     // 64   (total 1088 floats = 4352 B)
    for (int i = t; i < 384; i += 256) sWms[i] = Wm_s[i];
    if (t < 64) sWmv[t] = Wm_v[t];
    sWus[t] = Wu_s[t];
    if (t < 64) sWuv[t] = Wu_v[t];
    sWss[t] = Ws_s[t];
    if (t < 64) sWsv[t] = Ws_v[t];
    __syncthreads();
    float rs = res_scale_p[0];
    for (int vb = blockIdx.x; vb < nbN; vb += gridDim.x) {
      long long n = (long long)vb * 256 + t;
      if (n < N)
        node_body(n, x, xnorm, agg0, agg1, normb, sWms, sWmv, sWus, sWuv,
                  sWss, sWsv, rs, out);
    }
  }
}

// ==================== fallback kernels (R12 path) ====================
extern "C" __global__ __launch_bounds__(256) void k_pre(
    const float* __restrict__ x, float* __restrict__ xnorm,
    float* __restrict__ agg0, float* __restrict__ agg1,
    float* __restrict__ normb, const float* __restrict__ w_r2,
    f16* __restrict__ W2T, int N) {
  pre_body(blockIdx.x * 256 + threadIdx.x, x, xnorm, agg0, agg1, normb,
           w_r2, W2T, N);
}

extern "C" __global__ __launch_bounds__(256, 3) void k_edge(
    const float* __restrict__ xnorm,
    const int* __restrict__ esrc, const int* __restrict__ edst,
    const float* __restrict__ sh, const float* __restrict__ rbf,
    const float* __restrict__ elen,
    const float* __restrict__ w_r1, const float* __restrict__ b_r1,
    const float* __restrict__ w_g1, const float* __restrict__ b_g1,
    const float* __restrict__ w_g2, const float* __restrict__ b_g2,
    const float* __restrict__ b_r2, const f16* __restrict__ W2T,
    float* __restrict__ agg0, float* __restrict__ agg1,
    float* __restrict__ normb, int E) {
  __shared__ __align__(16) char smem[53248];
  edge_tile(smem, blockIdx.x, xnorm, esrc, edst, sh, rbf, elen, w_r1, b_r1,
            w_g1, b_g1, w_g2, b_g2, b_r2, W2T, agg0, agg1, normb, E);
}

extern "C" __global__ __launch_bounds__(256) void k_node(
    const float* __restrict__ x, const float* __restrict__ xnorm,
    const float* __restrict__ agg0, const float* __restrict__ agg1,
    const float* __restrict__ normb, const float* __restrict__ Wm_s,
    const float* __restrict__ Wm_v, const float* __restrict__ Wu_s,
    const float* __restrict__ Wu_v, const float* __restrict__ Ws_s,
    const float* __restrict__ Ws_v, const float* __restrict__ res_scale_p,
    float* __restrict__ out, int N) {
  __shared__ float sW[1088];
  int t = threadIdx.x;
  float* sWms = sW;
  float* sWmv = sW + 384;
  float* sWus = sW + 448;
  float* sWuv = sW + 704;
  float* sWss = sW + 768;
  float* sWsv = sW + 1024;
  for (int i = t; i < 384; i += 256) sWms[i] = Wm_s[i];
  if (t < 64) sWmv[t] = Wm_v[t];
  sWus[t] = Wu_s[t];
  if (t < 64) sWuv[t] = Wu_v[t];
  sWss[t] = Ws_s[t];
  if (t < 64) sWsv[t] = Ws_v[t];
  __syncthreads();
  long long n = (long long)blockIdx.x * 256 + t;
  if (n >= N) return;
  node_body(n, x, xnorm, agg0, agg1, normb, sWms, sWmv, sWus, sWuv, sWss,
            sWsv, res_scale_p[0], out);
}

// ==================== launch ====================
extern "C" void kernel_launch(void* const* d_in, const int* in_sizes, int n_in,
                              void* d_out, int out_size, void* d_ws, size_t ws_size,
                              hipStream_t stream) {
  const float* x = (const float*)d_in[0];
  const int* esrc = (const int*)d_in[1];
  const int* edst = (const int*)d_in[2];
  const float* sh = (const float*)d_in[3];
  const float* rbf = (const float*)d_in[4];
  const float* elen = (const float*)d_in[5];
  const float* w_r1 = (const float*)d_in[6];
  const float* b_r1 = (const float*)d_in[7];
  const float* w_r2 = (const float*)d_in[8];
  const float* b_r2 = (const float*)d_in[9];
  const float* w_g1 = (const float*)d_in[10];
  const float* b_g1 = (const float*)d_in[11];
  const float* w_g2 = (const float*)d_in[12];
  const float* b_g2 = (const float*)d_in[13];
  const float* Wm_s = (const float*)d_in[14];
  const float* Wm_v = (const float*)d_in[15];
  const float* Wu_s = (const float*)d_in[16];
  const float* Wu_v = (const float*)d_in[17];
  const float* Ws_s = (const float*)d_in[18];
  const float* Ws_v = (const float*)d_in[19];
  const float* res_scale = (const float*)d_in[20];

  const int N = in_sizes[0] / 40;
  const int E = in_sizes[1];

  char* ws = (char*)d_ws;
  size_t off = 0;
  float* xnorm = (float*)(ws + off); off += (size_t)N * 40 * sizeof(float);
  off = (off + 255) & ~(size_t)255;
  float* agg0 = (float*)(ws + off); off += (size_t)N * 16 * sizeof(float);
  float* agg1 = (float*)(ws + off); off += (size_t)N * 24 * sizeof(float);
  float* normb = (float*)(ws + off); off += (size_t)N * sizeof(float);
  off = (off + 255) & ~(size_t)255;
  f16* W2T = (f16*)(ws + off); off += (size_t)WNUM * 64 * sizeof(f16);

  int nbN256 = (N + 255) / 256;
  int nbPre = nbN256;  // N=50000 covers HID*WNUM=36864 threads too
  if ((HID * WNUM + 255) / 256 > nbPre) nbPre = (HID * WNUM + 255) / 256;
  int nblkE = (E + 127) / 128;

  // size the cooperative grid from the occupancy API (expected 3/CU -> 768)
  int blocksPerCU = 0;
  (void)hipOccupancyMaxActiveBlocksPerMultiprocessor(&blocksPerCU,
                                                     (const void*)k_mega, 256, 0);
  if (blocksPerCU < 1) blocksPerCU = 1;
  int numCU = 0, dev = 0;
  (void)hipGetDevice(&dev);
  (void)hipDeviceGetAttribute(&numCU, hipDeviceAttributeMultiprocessorCount, dev);
  if (numCU < 1) numCU = 256;
  int grid = blocksPerCU * numCU;
  if (grid > nblkE) grid = nblkE;

  int N_ = N, E_ = E, nbPre_ = nbPre, nblkE_ = nblkE, nbN_ = nbN256;
  float* outp = (float*)d_out;
  void* args[] = {
      (void*)&x,      (void*)&esrc,   (void*)&edst,   (void*)&sh,
      (void*)&rbf,    (void*)&elen,   (void*)&w_r1,   (void*)&b_r1,
      (void*)&w_g1,   (void*)&b_g1,   (void*)&w_g2,   (void*)&b_g2,
      (void*)&b_r2,   (void*)&w_r2,   (void*)&Wm_s,   (void*)&Wm_v,
      (void*)&Wu_s,   (void*)&Wu_v,   (void*)&Ws_s,   (void*)&Ws_v,
      (void*)&res_scale, (void*)&xnorm, (void*)&agg0, (void*)&agg1,
      (void*)&normb,  (void*)&W2T,    (void*)&outp,   (void*)&N_,
      (void*)&E_,     (void*)&nbPre_, (void*)&nblkE_, (void*)&nbN_};

  hipError_t err = hipLaunchCooperativeKernel(
      (const void*)k_mega, dim3(grid), dim3(256), args, 0, stream);

  if (err != hipSuccess) {
    // fallback: R12's 3-dispatch path
    k_pre<<<nbPre, 256, 0, stream>>>(x, xnorm, agg0, agg1, normb, w_r2, W2T, N);
    k_edge<<<nblkE, 256, 0, stream>>>(xnorm, esrc, edst, sh, rbf, elen,
                                      w_r1, b_r1, w_g1, b_g1, w_g2, b_g2,
                                      b_r2, W2T, agg0, agg1, normb, E);
    k_node<<<nbN256, 256, 0, stream>>>(x, xnorm, agg0, agg1, normb, Wm_s,
                                       Wm_v, Wu_s, Wu_v, Ws_s, Ws_v,
                                       res_scale, (float*)d_out, N);
  }
}

// Round 15
// 449.567 us; speedup vs baseline: 1.4396x; 1.4396x over previous
//
#include <hip/hip_runtime.h>
#include <cstdint>

#define MUL0 16
#define MUL1 8
#define NRBF 8
#define HID 64
#define WNUM 576
#define CUTOFF 5.0f
#define EPSF 1e-8f

#define INV_SQRT3 0.57735026918962576f
#define A_PATH    0.20412414523193154f   /* 1/sqrt(24) */
#define Q16       0.25f                  /* 1/sqrt(16) */
#define Q8        0.35355339059327373f   /* 1/sqrt(8)  */
#define PI_OVER_CUT 0.62831853071795865f /* pi/5 */

typedef _Float16 f16;
typedef _Float16 f16x8 __attribute__((ext_vector_type(8)));
typedef float f32x4 __attribute__((ext_vector_type(4)));

#define MFMA16(a, b, cc) __builtin_amdgcn_mfma_f32_16x16x32_f16(a, b, cc, 0, 0, 0)

__device__ __forceinline__ float sigm(float x) { return 1.0f / (1.0f + __expf(-x)); }

typedef __attribute__((address_space(1))) const unsigned char* gptr_t;
typedef __attribute__((address_space(3))) unsigned char* lptr_t;

// async global->LDS DMA, 16B per lane (m97). LDS dest wave-uniform; HW adds lane*16.
__device__ __forceinline__ void stage16(const void* g, void* l) {
  __builtin_amdgcn_global_load_lds((gptr_t)g, (lptr_t)l, 16, 0, 0);
}

// ---------------- fused pre-kernel: W2T transpose + xnorm + agg zero ----
// W2T pre-swizzle: within each 2048B jt-tile (16 rows x 128B), 16B chunk h of
// row c goes to slot h ^ (c&7); staged linearly to LDS, read with same XOR.
extern "C" __global__ __launch_bounds__(256) void k_pre(
    const float* __restrict__ x, float* __restrict__ xnorm,
    float* __restrict__ agg0, float* __restrict__ agg1,
    float* __restrict__ normb, const float* __restrict__ w_r2,
    f16* __restrict__ W2T, int N) {
  int gid = blockIdx.x * 256 + threadIdx.x;

  if (gid < HID * WNUM) {
    int n = gid >> 6, k = gid & 63;
    int jt = n >> 4, cc = n & 15;
    int h = k >> 3, e = k & 7;
    int dst = jt * 1024 + cc * 64 + ((h ^ (cc & 7)) << 3) + e;
    W2T[dst] = (f16)w_r2[k * WNUM + n];
  }

  if (gid < N) {
    long long n = gid;
    const float4* xr = (const float4*)(x + n * 40);
    float4 vv[10];
#pragma unroll
    for (int i = 0; i < 10; i++) vv[i] = xr[i];
    float* f = (float*)vv;
    float ss = 0.f, vs = 0.f;
#pragma unroll
    for (int i = 0; i < 16; i++) ss += f[i] * f[i];
#pragma unroll
    for (int i = 16; i < 40; i++) vs += f[i] * f[i];
    float sr = rsqrtf(ss * (1.0f / 16.0f) + EPSF);
    float vr = rsqrtf(vs * (1.0f / 8.0f) + EPSF);
#pragma unroll
    for (int i = 0; i < 16; i++) f[i] *= sr;
#pragma unroll
    for (int i = 16; i < 40; i++) f[i] *= vr;
    float4* o = (float4*)(xnorm + n * 40);
#pragma unroll
    for (int i = 0; i < 10; i++) o[i] = vv[i];
    float4 z = {0.f, 0.f, 0.f, 0.f};
    float4* pa0 = (float4*)(agg0 + n * 16);
#pragma unroll
    for (int i = 0; i < 4; i++) pa0[i] = z;
    float4* pa1 = (float4*)(agg1 + n * 24);
#pragma unroll
    for (int i = 0; i < 6; i++) pa1[i] = z;
    normb[n] = 0.f;
  }
}

// ---------------- fused edge kernel: W2T RESIDENT in LDS ----------------
// 4 waves/block, 128 edges/tile, grid-strided over tiles (~5-12 tiles/block).
// W2T (72KB, swizzled) + bias (2.3KB) staged into LDS ONCE per block via DMA;
// B-phase is pure conflict-free ds_read_b128 + MFMA: no staging, no ring,
// 3 barriers/tile (was 12). Occupancy drops to 1 block/CU (129KB LDS) --
// R7 proved k_edge is occupancy-insensitive 21-52%, trading TLP for a
// stall-free B-phase.
extern "C" __global__ __launch_bounds__(256, 1) void k_edge(
    const float* __restrict__ xnorm,
    const int* __restrict__ esrc, const int* __restrict__ edst,
    const float* __restrict__ sh, const float* __restrict__ rbf,
    const float* __restrict__ elen,
    const float* __restrict__ w_r1, const float* __restrict__ b_r1,
    const float* __restrict__ w_g1, const float* __restrict__ b_g1,
    const float* __restrict__ w_g2, const float* __restrict__ b_g2,
    const float* __restrict__ b_r2, const f16* __restrict__ W2T,
    float* __restrict__ agg0, float* __restrict__ agg1,
    float* __restrict__ normb, int E, int ntiles) {
  __shared__ __align__(16) char smem[129280];
  // A-phase arrays (53248 B), layouts verified R7-R12
  f16   (*s_H)[32][72]  = (f16(*)[32][72])(smem);             // 18432
  float (*s_sn)[32][20] = (float(*)[32][20])(smem + 18432);   // 10240
  float (*s_v)[32][26]  = (float(*)[32][26])(smem + 28672);   // 13312
  float (*s_a1)[32][10] = (float(*)[32][10])(smem + 41984);   //  5120
  float (*s_sh)[32][4]  = (float(*)[32][4])(smem + 47104);    //  2048
  float (*s_rbf)[32][8] = (float(*)[32][8])(smem + 49152);    //  4096
  char*  wlds  = smem + 53248;                                // 73728 (W2T)
  float* s_bias = (float*)(smem + 126976);                    //  2304 (576 f32)

  const int t = threadIdx.x;
  const int w = t >> 6;
  const int lane = t & 63;

  // ---- one-time: stage W2T (18 x 4KB DMA rounds) + bias ----
  {
    const char* W2Tc = (const char*)W2T;
#pragma unroll 1
    for (int k = 0; k < 18; k++)
      stage16(W2Tc + k * 4096 + w * 1024 + lane * 16,
              wlds + k * 4096 + w * 1024);
    for (int i = t; i < WNUM; i += 256) s_bias[i] = b_r2[i];
  }
  // (DMA drained by the vmcnt(0) the compiler emits at the first barrier below)

  const int quad = lane >> 4;
  const int c = lane & 15;
  const int rd0 = c * 128 + ((quad ^ (c & 7)) << 4);
  const int rd1 = c * 128 + (((quad + 4) ^ (c & 7)) << 4);

#pragma unroll 1
  for (int vb = blockIdx.x; vb < ntiles; vb += gridDim.x) {
    __syncthreads();   // prev tile's B reads done; also drains W2T DMA (1st iter)
    const long long eb = (long long)vb * 128 + w * 32;

    // ---- A0: direct coalesced edge loads ----
    int dstv = 0, srcv = 0;
    float lenv = 1e9f;
    if (lane < 32) {
      long long g2 = eb + lane;
      float4 shv = {0.f, 0.f, 0.f, 0.f};
      if (g2 < E) {
        srcv = esrc[g2];
        dstv = edst[g2];
        lenv = elen[g2];
        shv = *(const float4*)&sh[g2 * 4];
      }
      *(float4*)&s_sh[w][lane][0] = shv;
    }
    {
      int e = lane >> 1, half = lane & 1;
      long long ge2 = eb + e;
      float4 rv4 = {0.f, 0.f, 0.f, 0.f};
      if (ge2 < E) rv4 = *(const float4*)&rbf[ge2 * 8 + half * 4];
      *(float4*)&s_rbf[w][e][half * 4] = rv4;
    }
    __syncthreads();

    // ---- A1: gather xnorm + transform (4 lanes/edge, 2 groups) ----
    {
      const int ge_l = lane >> 2;
      const int part = lane & 3;
#pragma unroll
      for (int g = 0; g < 2; g++) {
        int e = g * 16 + ge_l;
        int srcn = __shfl(srcv, e);
        const float* xr = xnorm + (long long)srcn * 40;
        if (part < 2) {
          float4 aLo = *(const float4*)(xr + part * 8);
          float4 aHi = *(const float4*)(xr + part * 8 + 4);
          *(float4*)&s_sn[w][e][part * 8] = aLo;
          *(float4*)&s_sn[w][e][part * 8 + 4] = aHi;
        } else {
          const int i0 = (part - 2) * 4;
          const float* vp = xr + 16 + i0 * 3;
          float4 v0 = *(const float4*)(vp);
          float4 v1 = *(const float4*)(vp + 4);
          float4 v2 = *(const float4*)(vp + 8);
          *(float4*)&s_v[w][e][i0 * 3] = v0;
          *(float4*)&s_v[w][e][i0 * 3 + 4] = v1;
          *(float4*)&s_v[w][e][i0 * 3 + 8] = v2;
          float4 shq = *(const float4*)&s_sh[w][e][0];
          float s1x = shq.y, s1y = shq.z, s1z = shq.w;
          s_a1[w][e][i0]     = INV_SQRT3 * (v0.x * s1x + v0.y * s1y + v0.z * s1z);
          s_a1[w][e][i0 + 1] = INV_SQRT3 * (v0.w * s1x + v1.x * s1y + v1.y * s1z);
          s_a1[w][e][i0 + 2] = INV_SQRT3 * (v1.z * s1x + v1.w * s1y + v2.x * s1z);
          s_a1[w][e][i0 + 3] = INV_SQRT3 * (v2.y * s1x + v2.z * s1y + v2.w * s1z);
        }
      }
    }

    // ---- A2: hidden layer H (f16), lane = h, 32 edges ----
    {
      float wr[8];
#pragma unroll
      for (int r = 0; r < 8; r++) wr[r] = w_r1[r * HID + lane];
      float bh = b_r1[lane];
#pragma unroll 4
      for (int u = 0; u < 32; u++) {
        float4 ra = *(const float4*)&s_rbf[w][u][0];
        float4 rb2 = *(const float4*)&s_rbf[w][u][4];
        float acc = bh + ra.x * wr[0] + ra.y * wr[1] + ra.z * wr[2] + ra.w * wr[3]
                       + rb2.x * wr[4] + rb2.y * wr[5] + rb2.z * wr[6] + rb2.w * wr[7];
        s_H[w][u][lane] = (f16)(acc * sigm(acc));
      }
    }

    // ---- A3: gate MLP, 2 lanes/edge x 32 h-units ----
    float ewv = 0.f;
    {
      const int eg = lane & 31;
      const int hf = lane >> 5;
      float4 ga = *(const float4*)&s_rbf[w][eg][0];
      float4 gb = *(const float4*)&s_rbf[w][eg][4];
      float rv[8] = {ga.x, ga.y, ga.z, ga.w, gb.x, gb.y, gb.z, gb.w};
      float accp = 0.f;
#pragma unroll
      for (int ch = 0; ch < 2; ch++) {
        const int base = hf * 32 + ch * 16;
        float ttv[16];
        {
          const float4 b0 = *(const float4*)&b_g1[base];
          const float4 b1 = *(const float4*)&b_g1[base + 4];
          const float4 b2 = *(const float4*)&b_g1[base + 8];
          const float4 b3 = *(const float4*)&b_g1[base + 12];
          ttv[0] = b0.x; ttv[1] = b0.y; ttv[2] = b0.z; ttv[3] = b0.w;
          ttv[4] = b1.x; ttv[5] = b1.y; ttv[6] = b1.z; ttv[7] = b1.w;
          ttv[8] = b2.x; ttv[9] = b2.y; ttv[10] = b2.z; ttv[11] = b2.w;
          ttv[12] = b3.x; ttv[13] = b3.y; ttv[14] = b3.z; ttv[15] = b3.w;
        }
#pragma unroll
        for (int r = 0; r < 8; r++) {
          const float* wg = w_g1 + r * HID + base;
          float4 w0 = *(const float4*)(wg);
          float4 w1 = *(const float4*)(wg + 4);
          float4 w2 = *(const float4*)(wg + 8);
          float4 w3 = *(const float4*)(wg + 12);
          float rr = rv[r];
          ttv[0] += rr * w0.x; ttv[1] += rr * w0.y; ttv[2] += rr * w0.z; ttv[3] += rr * w0.w;
          ttv[4] += rr * w1.x; ttv[5] += rr * w1.y; ttv[6] += rr * w1.z; ttv[7] += rr * w1.w;
          ttv[8] += rr * w2.x; ttv[9] += rr * w2.y; ttv[10] += rr * w2.z; ttv[11] += rr * w2.w;
          ttv[12] += rr * w3.x; ttv[13] += rr * w3.y; ttv[14] += rr * w3.z; ttv[15] += rr * w3.w;
        }
        const float4 g0 = *(const float4*)&w_g2[base];
        const float4 g1 = *(const float4*)&w_g2[base + 4];
        const float4 g2 = *(const float4*)&w_g2[base + 8];
        const float4 g3 = *(const float4*)&w_g2[base + 12];
        float gw[16] = {g0.x, g0.y, g0.z, g0.w, g1.x, g1.y, g1.z, g1.w,
                        g2.x, g2.y, g2.z, g2.w, g3.x, g3.y, g3.z, g3.w};
#pragma unroll
        for (int k = 0; k < 16; k++) accp += ttv[k] * sigm(ttv[k]) * gw[k];
      }
      accp += __shfl_xor(accp, 32);
      if (lane < 32) {
        long long g2e = eb + lane;
        if (g2e < E) {
          float cw = (lenv < CUTOFF) ? 0.5f * (__cosf(PI_OVER_CUT * lenv) + 1.0f) : 0.f;
          ewv = cw * sigm(accp + b_g2[0]);
        }
      }
    }
    __syncthreads();

    // ---- B: af regs + 36 jt from RESIDENT W2T (no staging, no barriers) ----
    const f16x8 af00 = *(const f16x8*)&s_H[w][c][quad * 8];
    const f16x8 af01 = *(const f16x8*)&s_H[w][c][32 + quad * 8];
    const f16x8 af10 = *(const f16x8*)&s_H[w][16 + c][quad * 8];
    const f16x8 af11 = *(const f16x8*)&s_H[w][16 + c][32 + quad * 8];

    float p1[2][4] = {{0.f}}, p2[2][4] = {{0.f}}, t3[2][4] = {{0.f}};
    float mx[2][4] = {{0.f}}, my[2][4] = {{0.f}}, mz[2][4] = {{0.f}};

#pragma unroll 2
    for (int jt = 0; jt < 16; jt++) {
      const char* tb = wlds + jt * 2048;
      f16x8 b0 = *(const f16x8*)(tb + rd0);
      f16x8 b1 = *(const f16x8*)(tb + rd1);
      float bias = s_bias[jt * 16 + c];
      f32x4 C0 = {0.f, 0.f, 0.f, 0.f};
      C0 = MFMA16(af00, b0, C0); C0 = MFMA16(af01, b1, C0);
      f32x4 C1 = {0.f, 0.f, 0.f, 0.f};
      C1 = MFMA16(af10, b0, C1); C1 = MFMA16(af11, b1, C1);
#pragma unroll
      for (int r = 0; r < 4; r++) {
        p1[0][r] += s_sn[w][quad * 4 + r][jt] * (C0[r] + bias);
        p1[1][r] += s_sn[w][16 + quad * 4 + r][jt] * (C1[r] + bias);
      }
    }
#pragma unroll 2
    for (int jt = 16; jt < 24; jt++) {
      const char* tb = wlds + jt * 2048;
      f16x8 b0 = *(const f16x8*)(tb + rd0);
      f16x8 b1 = *(const f16x8*)(tb + rd1);
      float bias = s_bias[jt * 16 + c];
      f32x4 C0 = {0.f, 0.f, 0.f, 0.f};
      C0 = MFMA16(af00, b0, C0); C0 = MFMA16(af01, b1, C0);
      f32x4 C1 = {0.f, 0.f, 0.f, 0.f};
      C1 = MFMA16(af10, b0, C1); C1 = MFMA16(af11, b1, C1);
      const int i = jt - 16;
#pragma unroll
      for (int r = 0; r < 4; r++) {
        p2[0][r] += s_a1[w][quad * 4 + r][i] * (C0[r] + bias);
        p2[1][r] += s_a1[w][16 + quad * 4 + r][i] * (C1[r] + bias);
      }
    }
#pragma unroll 2
    for (int jt = 24; jt < 32; jt++) {
      const char* tb = wlds + jt * 2048;
      f16x8 b0 = *(const f16x8*)(tb + rd0);
      f16x8 b1 = *(const f16x8*)(tb + rd1);
      float bias = s_bias[jt * 16 + c];
      f32x4 C0 = {0.f, 0.f, 0.f, 0.f};
      C0 = MFMA16(af00, b0, C0); C0 = MFMA16(af01, b1, C0);
      f32x4 C1 = {0.f, 0.f, 0.f, 0.f};
      C1 = MFMA16(af10, b0, C1); C1 = MFMA16(af11, b1, C1);
      const int i = (jt - 24) * 2 + (c >> 3);
#pragma unroll
      for (int r = 0; r < 4; r++) {
        t3[0][r] += s_sn[w][quad * 4 + r][i] * (C0[r] + bias);
        t3[1][r] += s_sn[w][16 + quad * 4 + r][i] * (C1[r] + bias);
      }
    }
#pragma unroll 2
    for (int jt = 32; jt < 36; jt++) {
      const char* tb = wlds + jt * 2048;
      f16x8 b0 = *(const f16x8*)(tb + rd0);
      f16x8 b1 = *(const f16x8*)(tb + rd1);
      float bias = s_bias[jt * 16 + c];
      f32x4 C0 = {0.f, 0.f, 0.f, 0.f};
      C0 = MFMA16(af00, b0, C0); C0 = MFMA16(af01, b1, C0);
      f32x4 C1 = {0.f, 0.f, 0.f, 0.f};
      C1 = MFMA16(af10, b0, C1); C1 = MFMA16(af11, b1, C1);
      const int i = (jt - 32) * 2 + (c >> 3);
#pragma unroll
      for (int r = 0; r < 4; r++) {
        float wv0 = C0[r] + bias;
        float wv1 = C1[r] + bias;
        mx[0][r] += s_v[w][quad * 4 + r][3 * i] * wv0;
        my[0][r] += s_v[w][quad * 4 + r][3 * i + 1] * wv0;
        mz[0][r] += s_v[w][quad * 4 + r][3 * i + 2] * wv0;
        mx[1][r] += s_v[w][16 + quad * 4 + r][3 * i] * wv1;
        my[1][r] += s_v[w][16 + quad * 4 + r][3 * i + 1] * wv1;
        mz[1][r] += s_v[w][16 + quad * 4 + r][3 * i + 2] * wv1;
      }
    }

    // fold the two column-halves (c and c^8 share output j = c&7)
#pragma unroll
    for (int g = 0; g < 2; g++)
#pragma unroll
      for (int r = 0; r < 4; r++) {
        t3[g][r] += __shfl_xor(t3[g][r], 8);
        mx[g][r] += __shfl_xor(mx[g][r], 8);
        my[g][r] += __shfl_xor(my[g][r], 8);
        mz[g][r] += __shfl_xor(mz[g][r], 8);
      }

    // ---- epilogue: atomic scatter (run-compression kept; harmless unsorted) ----
#pragma unroll
    for (int g = 0; g < 2; g++) {
      const int e0g = g * 16 + quad * 4;
      int cur = __shfl(dstv, e0g);
      float acc0 = 0.f, a1x = 0.f, a1y = 0.f, a1z = 0.f, nacc = 0.f;
#pragma unroll
      for (int r = 0; r < 4; r++) {
        const int e = e0g + r;
        const int dst = __shfl(dstv, e);
        const float ew = __shfl(ewv, e);
        if (dst != cur) {
          atomicAdd(&agg0[(long long)cur * 16 + c], acc0);
          if (c < 8) {
            long long b = (long long)cur * 24 + (long long)c * 3;
            atomicAdd(&agg1[b], a1x);
            atomicAdd(&agg1[b + 1], a1y);
            atomicAdd(&agg1[b + 2], a1z);
          } else if (c == 8) {
            atomicAdd(&normb[cur], nacc);
          }
          acc0 = a1x = a1y = a1z = nacc = 0.f;
          cur = dst;
        }
        float sc2 = A_PATH * ew;
        float sh0 = s_sh[w][e][0];
        acc0 += (sh0 * p1[g][r] + p2[g][r]) * sc2;
        if (c < 8) {
          float t3v = t3[g][r] * sc2;
          float scs = sc2 * sh0;
          a1x += t3v * s_sh[w][e][1] + mx[g][r] * scs;
          a1y += t3v * s_sh[w][e][2] + my[g][r] * scs;
          a1z += t3v * s_sh[w][e][3] + mz[g][r] * scs;
        } else if (c == 8) {
          nacc += ew;
        }
      }
      atomicAdd(&agg0[(long long)cur * 16 + c], acc0);
      if (c < 8) {
        long long b = (long long)cur * 24 + (long long)c * 3;
        atomicAdd(&agg1[b], a1x);
        atomicAdd(&agg1[b + 1], a1y);
        atomicAdd(&agg1[b + 2], a1z);
      } else if (c == 8) {
        atomicAdd(&normb[cur], nacc);
      }
    }
  }
}

// ---------------- final node kernel ----------------
extern "C" __global__ __launch_bounds__(64) void k_node(
    const float* __restrict__ x, const float* __restrict__ xnorm,
    const float* __restrict__ agg0, const float* __restrict__ agg1,
    const float* __restrict__ normb, const float* __restrict__ Wm_s,
    const float* __restrict__ Wm_v, const float* __restrict__ Wu_s,
    const float* __restrict__ Wu_v, const float* __restrict__ Ws_s,
    const float* __restrict__ Ws_v, const float* __restrict__ res_scale_p,
    float* __restrict__ out, int N) {
  __shared__ float sWms[384];
  __shared__ float sWmv[64];
  __shared__ float sWus[256];
  __shared__ float sWuv[64];
  __shared__ float sWss[256];
  __shared__ float sWsv[64];
  int t = threadIdx.x;
  for (int i = t; i < 384; i += 64) sWms[i] = Wm_s[i];
  sWmv[t] = Wm_v[t];
  for (int i = t; i < 256; i += 64) sWus[i] = Wu_s[i];
  sWuv[t] = Wu_v[t];
  for (int i = t; i < 256; i += 64) sWss[i] = Ws_s[i];
  sWsv[t] = Ws_v[t];
  __syncthreads();
  int n = blockIdx.x * 64 + t;
  if (n >= N) return;

  float inv = 1.0f / fmaxf(normb[n], EPSF);
  float4 a04[4], a14[6];
  {
    const float4* p = (const float4*)(agg0 + (long long)n * 16);
#pragma unroll
    for (int i = 0; i < 4; i++) a04[i] = p[i];
    const float4* q = (const float4*)(agg1 + (long long)n * 24);
#pragma unroll
    for (int i = 0; i < 6; i++) a14[i] = q[i];
  }
  float* a0 = (float*)a04;
  float* a1 = (float*)a14;
#pragma unroll
  for (int i = 0; i < 16; i++) a0[i] *= inv;
#pragma unroll
  for (int i = 0; i < 24; i++) a1[i] *= inv;

  float scal[16], gate[8];
#pragma unroll
  for (int jj = 0; jj < 24; jj++) {
    float acc = 0.f;
#pragma unroll
    for (int i = 0; i < 16; i++) acc += a0[i] * sWms[i * 24 + jj];
    acc *= Q16;
    if (jj < 16) scal[jj] = acc * sigm(acc);
    else gate[jj - 16] = sigm(acc);
  }
  float vg[24];
#pragma unroll
  for (int j = 0; j < 8; j++) {
    float g = gate[j];
#pragma unroll
    for (int cc = 0; cc < 3; cc++) {
      float acc = 0.f;
#pragma unroll
      for (int i = 0; i < 8; i++) acc += a1[i * 3 + cc] * sWmv[i * 8 + j];
      vg[j * 3 + cc] = acc * Q8 * g;
    }
  }
  float4 xn4[10], xo4[10];
  {
    const float4* p = (const float4*)(xnorm + (long long)n * 40);
    const float4* q = (const float4*)(x + (long long)n * 40);
#pragma unroll
    for (int i = 0; i < 10; i++) { xn4[i] = p[i]; xo4[i] = q[i]; }
  }
  const float* xn = (const float*)xn4;
  const float* xo = (const float*)xo4;
  float rs = res_scale_p[0];

  float4 ob[10];
  float* ov = (float*)ob;
#pragma unroll
  for (int j = 0; j < 16; j++) {
    float acc = 0.f, acc2 = 0.f;
#pragma unroll
    for (int i = 0; i < 16; i++) {
      acc += scal[i] * sWus[i * 16 + j];
      acc2 += xn[i] * sWss[i * 16 + j];
    }
    ov[j] = xo[j] + rs * ((acc + acc2) * Q16);
  }
#pragma unroll
  for (int j = 0; j < 8; j++) {
#pragma unroll
    for (int cc = 0; cc < 3; cc++) {
      float acc = 0.f;
#pragma unroll
      for (int i = 0; i < 8; i++)
        acc += vg[i * 3 + cc] * sWuv[i * 8 + j] + xn[16 + i * 3 + cc] * sWsv[i * 8 + j];
      ov[16 + j * 3 + cc] = xo[16 + j * 3 + cc] + rs * (acc * Q8);
    }
  }
  float4* po = (float4*)(out + (long long)n * 40);
#pragma unroll
  for (int i = 0; i < 10; i++) po[i] = ob[i];
}

// ---------------- launch: 3 dispatches ----------------
extern "C" void kernel_launch(void* const* d_in, const int* in_sizes, int n_in,
                              void* d_out, int out_size, void* d_ws, size_t ws_size,
                              hipStream_t stream) {
  const float* x = (const float*)d_in[0];
  const int* esrc = (const int*)d_in[1];
  const int* edst = (const int*)d_in[2];
  const float* sh = (const float*)d_in[3];
  const float* rbf = (const float*)d_in[4];
  const float* elen = (const float*)d_in[5];
  const float* w_r1 = (const float*)d_in[6];
  const float* b_r1 = (const float*)d_in[7];
  const float* w_r2 = (const float*)d_in[8];
  const float* b_r2 = (const float*)d_in[9];
  const float* w_g1 = (const float*)d_in[10];
  const float* b_g1 = (const float*)d_in[11];
  const float* w_g2 = (const float*)d_in[12];
  const float* b_g2 = (const float*)d_in[13];
  const float* Wm_s = (const float*)d_in[14];
  const float* Wm_v = (const float*)d_in[15];
  const float* Wu_s = (const float*)d_in[16];
  const float* Wu_v = (const float*)d_in[17];
  const float* Ws_s = (const float*)d_in[18];
  const float* Ws_v = (const float*)d_in[19];
  const float* res_scale = (const float*)d_in[20];

  const int N = in_sizes[0] / 40;
  const int E = in_sizes[1];

  char* ws = (char*)d_ws;
  size_t off = 0;
  float* xnorm = (float*)(ws + off); off += (size_t)N * 40 * sizeof(float);
  off = (off + 255) & ~(size_t)255;
  float* agg0 = (float*)(ws + off); off += (size_t)N * 16 * sizeof(float);
  float* agg1 = (float*)(ws + off); off += (size_t)N * 24 * sizeof(float);
  float* normb = (float*)(ws + off); off += (size_t)N * sizeof(float);
  off = (off + 255) & ~(size_t)255;
  f16* W2T = (f16*)(ws + off); off += (size_t)WNUM * 64 * sizeof(f16);

  const int nbN = (N + 255) / 256;

  k_pre<<<nbN, 256, 0, stream>>>(x, xnorm, agg0, agg1, normb, w_r2, W2T, N);

  int ntiles = (E + 127) / 128;
  int gridE = ntiles < 640 ? ntiles : 640;   // grid-strided, ~5 tiles/block
  k_edge<<<gridE, 256, 0, stream>>>(xnorm, esrc, edst, sh, rbf, elen,
                                    w_r1, b_r1, w_g1, b_g1, w_g2, b_g2, b_r2,
                                    W2T, agg0, agg1, normb, E, ntiles);

  k_node<<<(N + 63) / 64, 64, 0, stream>>>(x, xnorm, agg0, agg1, normb, Wm_s,
                                           Wm_v, Wu_s, Wu_v, Ws_s, Ws_v,
                                           res_scale, (float*)d_out, N);
}

// Round 16
// 328.095 us; speedup vs baseline: 1.9725x; 1.3702x over previous
//
#include <hip/hip_runtime.h>
#include <cstdint>

#define MUL0 16
#define MUL1 8
#define NRBF 8
#define HID 64
#define WNUM 576
#define CUTOFF 5.0f
#define EPSF 1e-8f

#define INV_SQRT3 0.57735026918962576f
#define A_PATH    0.20412414523193154f   /* 1/sqrt(24) */
#define Q16       0.25f                  /* 1/sqrt(16) */
#define Q8        0.35355339059327373f   /* 1/sqrt(8)  */
#define PI_OVER_CUT 0.62831853071795865f /* pi/5 */

typedef _Float16 f16;
typedef _Float16 f16x8 __attribute__((ext_vector_type(8)));
typedef float f32x4 __attribute__((ext_vector_type(4)));

#define MFMA16(a, b, cc) __builtin_amdgcn_mfma_f32_16x16x32_f16(a, b, cc, 0, 0, 0)

__device__ __forceinline__ float sigm(float x) { return 1.0f / (1.0f + __expf(-x)); }

typedef __attribute__((address_space(1))) const unsigned char* gptr_t;
typedef __attribute__((address_space(3))) unsigned char* lptr_t;

// async global->LDS DMA, 16B per lane, no staging registers (m97 pattern).
// LDS dest must be wave-uniform; HW adds lane*16.
__device__ __forceinline__ void stage16(const void* g, void* l) {
  __builtin_amdgcn_global_load_lds((gptr_t)g, (lptr_t)l, 16, 0, 0);
}

// ---------------- fused pre-kernel: W2T transpose + xnorm + agg zero ----
// W2T pre-swizzle: within each 2048B jt-tile (16 rows x 128B), 16B chunk h of
// row c goes to slot h ^ (c&7); staged linearly to LDS, read with same XOR.
extern "C" __global__ __launch_bounds__(256) void k_pre(
    const float* __restrict__ x, float* __restrict__ xnorm,
    float* __restrict__ agg0, float* __restrict__ agg1,
    float* __restrict__ normb, const float* __restrict__ w_r2,
    f16* __restrict__ W2T, int N) {
  int gid = blockIdx.x * 256 + threadIdx.x;

  if (gid < HID * WNUM) {
    int n = gid >> 6, k = gid & 63;
    int jt = n >> 4, cc = n & 15;
    int h = k >> 3, e = k & 7;
    int dst = jt * 1024 + cc * 64 + ((h ^ (cc & 7)) << 3) + e;
    W2T[dst] = (f16)w_r2[k * WNUM + n];
  }

  if (gid < N) {
    long long n = gid;
    const float4* xr = (const float4*)(x + n * 40);
    float4 vv[10];
#pragma unroll
    for (int i = 0; i < 10; i++) vv[i] = xr[i];
    float* f = (float*)vv;
    float ss = 0.f, vs = 0.f;
#pragma unroll
    for (int i = 0; i < 16; i++) ss += f[i] * f[i];
#pragma unroll
    for (int i = 16; i < 40; i++) vs += f[i] * f[i];
    float sr = rsqrtf(ss * (1.0f / 16.0f) + EPSF);
    float vr = rsqrtf(vs * (1.0f / 8.0f) + EPSF);
#pragma unroll
    for (int i = 0; i < 16; i++) f[i] *= sr;
#pragma unroll
    for (int i = 16; i < 40; i++) f[i] *= vr;
    float4* o = (float4*)(xnorm + n * 40);
#pragma unroll
    for (int i = 0; i < 10; i++) o[i] = vv[i];
    float4 z = {0.f, 0.f, 0.f, 0.f};
    float4* pa0 = (float4*)(agg0 + n * 16);
#pragma unroll
    for (int i = 0; i < 4; i++) pa0[i] = z;
    float4* pa1 = (float4*)(agg1 + n * 24);
#pragma unroll
    for (int i = 0; i < 6; i++) pa1[i] = z;
    normb[n] = 0.f;
  }
}

// ---------------- fused edge kernel (R12-verified structure) ----------
// 4 waves/block, 32 edges/wave. B-phase W2T via double-buffered 2x8KB LDS
// ring staged with global_load_lds DMA (R10/R11: no spills, latency hidden).
// Ring aliases dead s_H; bias aliases dead s_rbf; 9 barrier drains.
// R16: epilogue atomics split across the c/c^8 half-waves (post-fold both
// hold identical sums) -> max serial atomic chain 4 -> 3.
extern "C" __global__ __launch_bounds__(256, 3) void k_edge(
    const float* __restrict__ xnorm,
    const int* __restrict__ esrc, const int* __restrict__ edst,
    const float* __restrict__ sh, const float* __restrict__ rbf,
    const float* __restrict__ elen,
    const float* __restrict__ w_r1, const float* __restrict__ b_r1,
    const float* __restrict__ w_g1, const float* __restrict__ b_g1,
    const float* __restrict__ w_g2, const float* __restrict__ b_g2,
    const float* __restrict__ b_r2, const f16* __restrict__ W2T,
    float* __restrict__ agg0, float* __restrict__ agg1,
    float* __restrict__ normb, int E) {
  __shared__ __align__(16) char smem[53248];
  f16   (*s_H)[32][72]  = (f16(*)[32][72])(smem);             // 18432 (dead in B)
  float (*s_sn)[32][20] = (float(*)[32][20])(smem + 18432);   // 10240
  float (*s_v)[32][26]  = (float(*)[32][26])(smem + 28672);   // 13312
  float (*s_a1)[32][10] = (float(*)[32][10])(smem + 41984);   //  5120
  float (*s_sh)[32][4]  = (float(*)[32][4])(smem + 47104);    //  2048
  float (*s_rbf)[32][8] = (float(*)[32][8])(smem + 49152);    //  4096 (dead in B)
  float* s_bias = (float*)(smem + 49152);                     // aliases s_rbf

  const int t = threadIdx.x;
  const int w = t >> 6;
  const int lane = t & 63;
  const long long eb = (long long)blockIdx.x * 128 + w * 32;

  // ---- A0: direct coalesced edge loads (OOB edges -> zeros, ew forced 0) ----
  int dstv = 0, srcv = 0;
  float lenv = 1e9f;
  if (lane < 32) {
    long long g2 = eb + lane;
    float4 shv = {0.f, 0.f, 0.f, 0.f};
    if (g2 < E) {
      srcv = esrc[g2];
      dstv = edst[g2];
      lenv = elen[g2];
      shv = *(const float4*)&sh[g2 * 4];
    }
    *(float4*)&s_sh[w][lane][0] = shv;
  }
  {
    int e = lane >> 1, half = lane & 1;
    long long ge2 = eb + e;
    float4 rv4 = {0.f, 0.f, 0.f, 0.f};
    if (ge2 < E) rv4 = *(const float4*)&rbf[ge2 * 8 + half * 4];
    *(float4*)&s_rbf[w][e][half * 4] = rv4;
  }
  __syncthreads();

  // ---- A1: gather xnorm + transform (4 lanes/edge, 2 groups) ----
  {
    const int ge_l = lane >> 2;
    const int part = lane & 3;
#pragma unroll
    for (int g = 0; g < 2; g++) {
      int e = g * 16 + ge_l;
      int srcn = __shfl(srcv, e);
      const float* xr = xnorm + (long long)srcn * 40;
      if (part < 2) {
        float4 aLo = *(const float4*)(xr + part * 8);
        float4 aHi = *(const float4*)(xr + part * 8 + 4);
        *(float4*)&s_sn[w][e][part * 8] = aLo;
        *(float4*)&s_sn[w][e][part * 8 + 4] = aHi;
      } else {
        const int i0 = (part - 2) * 4;
        const float* vp = xr + 16 + i0 * 3;
        float4 v0 = *(const float4*)(vp);
        float4 v1 = *(const float4*)(vp + 4);
        float4 v2 = *(const float4*)(vp + 8);
        *(float4*)&s_v[w][e][i0 * 3] = v0;
        *(float4*)&s_v[w][e][i0 * 3 + 4] = v1;
        *(float4*)&s_v[w][e][i0 * 3 + 8] = v2;
        float4 shq = *(const float4*)&s_sh[w][e][0];
        float s1x = shq.y, s1y = shq.z, s1z = shq.w;
        s_a1[w][e][i0]     = INV_SQRT3 * (v0.x * s1x + v0.y * s1y + v0.z * s1z);
        s_a1[w][e][i0 + 1] = INV_SQRT3 * (v0.w * s1x + v1.x * s1y + v1.y * s1z);
        s_a1[w][e][i0 + 2] = INV_SQRT3 * (v1.z * s1x + v1.w * s1y + v2.x * s1z);
        s_a1[w][e][i0 + 3] = INV_SQRT3 * (v2.y * s1x + v2.z * s1y + v2.w * s1z);
      }
    }
  }

  // ---- A2: hidden layer H (f16), lane = h, 32 edges ----
  {
    float wr[8];
#pragma unroll
    for (int r = 0; r < 8; r++) wr[r] = w_r1[r * HID + lane];
    float bh = b_r1[lane];
#pragma unroll 4
    for (int u = 0; u < 32; u++) {
      float4 ra = *(const float4*)&s_rbf[w][u][0];
      float4 rb2 = *(const float4*)&s_rbf[w][u][4];
      float acc = bh + ra.x * wr[0] + ra.y * wr[1] + ra.z * wr[2] + ra.w * wr[3]
                     + rb2.x * wr[4] + rb2.y * wr[5] + rb2.z * wr[6] + rb2.w * wr[7];
      s_H[w][u][lane] = (f16)(acc * sigm(acc));
    }
  }

  // ---- A3: gate MLP, 2 lanes/edge x 32 h-units ----
  float ewv = 0.f;
  {
    const int eg = lane & 31;
    const int hf = lane >> 5;
    float4 ga = *(const float4*)&s_rbf[w][eg][0];
    float4 gb = *(const float4*)&s_rbf[w][eg][4];
    float rv[8] = {ga.x, ga.y, ga.z, ga.w, gb.x, gb.y, gb.z, gb.w};
    float accp = 0.f;
#pragma unroll
    for (int ch = 0; ch < 2; ch++) {
      const int base = hf * 32 + ch * 16;
      float ttv[16];
      {
        const float4 b0 = *(const float4*)&b_g1[base];
        const float4 b1 = *(const float4*)&b_g1[base + 4];
        const float4 b2 = *(const float4*)&b_g1[base + 8];
        const float4 b3 = *(const float4*)&b_g1[base + 12];
        ttv[0] = b0.x; ttv[1] = b0.y; ttv[2] = b0.z; ttv[3] = b0.w;
        ttv[4] = b1.x; ttv[5] = b1.y; ttv[6] = b1.z; ttv[7] = b1.w;
        ttv[8] = b2.x; ttv[9] = b2.y; ttv[10] = b2.z; ttv[11] = b2.w;
        ttv[12] = b3.x; ttv[13] = b3.y; ttv[14] = b3.z; ttv[15] = b3.w;
      }
#pragma unroll
      for (int r = 0; r < 8; r++) {
        const float* wg = w_g1 + r * HID + base;
        float4 w0 = *(const float4*)(wg);
        float4 w1 = *(const float4*)(wg + 4);
        float4 w2 = *(const float4*)(wg + 8);
        float4 w3 = *(const float4*)(wg + 12);
        float rr = rv[r];
        ttv[0] += rr * w0.x; ttv[1] += rr * w0.y; ttv[2] += rr * w0.z; ttv[3] += rr * w0.w;
        ttv[4] += rr * w1.x; ttv[5] += rr * w1.y; ttv[6] += rr * w1.z; ttv[7] += rr * w1.w;
        ttv[8] += rr * w2.x; ttv[9] += rr * w2.y; ttv[10] += rr * w2.z; ttv[11] += rr * w2.w;
        ttv[12] += rr * w3.x; ttv[13] += rr * w3.y; ttv[14] += rr * w3.z; ttv[15] += rr * w3.w;
      }
      const float4 g0 = *(const float4*)&w_g2[base];
      const float4 g1 = *(const float4*)&w_g2[base + 4];
      const float4 g2 = *(const float4*)&w_g2[base + 8];
      const float4 g3 = *(const float4*)&w_g2[base + 12];
      float gw[16] = {g0.x, g0.y, g0.z, g0.w, g1.x, g1.y, g1.z, g1.w,
                      g2.x, g2.y, g2.z, g2.w, g3.x, g3.y, g3.z, g3.w};
#pragma unroll
      for (int k = 0; k < 16; k++) accp += ttv[k] * sigm(ttv[k]) * gw[k];
    }
    accp += __shfl_xor(accp, 32);
    if (lane < 32) {
      long long g2e = eb + lane;
      if (g2e < E) {
        float cw = (lenv < CUTOFF) ? 0.5f * (__cosf(PI_OVER_CUT * lenv) + 1.0f) : 0.f;
        ewv = cw * sigm(accp + b_g2[0]);
      }
    }
  }
  __syncthreads();

  // ---- B prologue: af regs + bias to LDS, then free s_H for the ring ----
  const int quad = lane >> 4;
  const int c = lane & 15;

  const f16x8 af00 = *(const f16x8*)&s_H[w][c][quad * 8];
  const f16x8 af01 = *(const f16x8*)&s_H[w][c][32 + quad * 8];
  const f16x8 af10 = *(const f16x8*)&s_H[w][16 + c][quad * 8];
  const f16x8 af11 = *(const f16x8*)&s_H[w][16 + c][32 + quad * 8];
  for (int i = t; i < WNUM; i += 256) s_bias[i] = b_r2[i];
  __syncthreads();   // af reads done; bias visible; ring may overwrite s_H

  char* ring = smem;                      // 2 x 8192B buffers
  const char* W2Tc = (const char*)W2T;
  const int lofs = w * 1024;              // wave-uniform LDS segment
  const int gofs = w * 1024 + lane * 16;  // per-lane global offset

  // chunk 0 (8KB = two 4KB halves; each wave stages 1KB per half)
  stage16(W2Tc + gofs, ring + lofs);
  stage16(W2Tc + 4096 + gofs, ring + 4096 + lofs);

  const int rd0 = c * 128 + ((quad ^ (c & 7)) << 4);
  const int rd1 = c * 128 + (((quad + 4) ^ (c & 7)) << 4);

  float p1[2][4] = {{0.f}}, p2[2][4] = {{0.f}}, t3[2][4] = {{0.f}};
  float mx[2][4] = {{0.f}}, my[2][4] = {{0.f}}, mz[2][4] = {{0.f}};

  // 9 chunks of 8KB = 4 jt-tiles each. Class boundaries align to chunks:
  // ch 0..3 -> jt 0..15 (p1), ch 4..5 -> jt 16..23 (p2),
  // ch 6..7 -> jt 24..31 (t3), ch 8 -> jt 32..35 (m*).
#pragma unroll 1
  for (int ch = 0; ch < 4; ch++) {
    __syncthreads();
    stage16(W2Tc + (ch + 1) * 8192 + gofs, ring + ((ch + 1) & 1) * 8192 + lofs);
    stage16(W2Tc + (ch + 1) * 8192 + 4096 + gofs,
            ring + ((ch + 1) & 1) * 8192 + 4096 + lofs);
    const char* bb = ring + (ch & 1) * 8192;
#pragma unroll
    for (int q = 0; q < 4; q++) {
      const int jt = ch * 4 + q;
      const char* tb = bb + q * 2048;
      f16x8 b0 = *(const f16x8*)(tb + rd0);
      f16x8 b1 = *(const f16x8*)(tb + rd1);
      float bias = s_bias[jt * 16 + c];
      f32x4 C0 = {0.f, 0.f, 0.f, 0.f};
      C0 = MFMA16(af00, b0, C0); C0 = MFMA16(af01, b1, C0);
      f32x4 C1 = {0.f, 0.f, 0.f, 0.f};
      C1 = MFMA16(af10, b0, C1); C1 = MFMA16(af11, b1, C1);
#pragma unroll
      for (int r = 0; r < 4; r++) {
        p1[0][r] += s_sn[w][quad * 4 + r][jt] * (C0[r] + bias);
        p1[1][r] += s_sn[w][16 + quad * 4 + r][jt] * (C1[r] + bias);
      }
    }
  }
#pragma unroll 1
  for (int ch = 4; ch < 6; ch++) {
    __syncthreads();
    stage16(W2Tc + (ch + 1) * 8192 + gofs, ring + ((ch + 1) & 1) * 8192 + lofs);
    stage16(W2Tc + (ch + 1) * 8192 + 4096 + gofs,
            ring + ((ch + 1) & 1) * 8192 + 4096 + lofs);
    const char* bb = ring + (ch & 1) * 8192;
#pragma unroll
    for (int q = 0; q < 4; q++) {
      const int jt = ch * 4 + q;
      const char* tb = bb + q * 2048;
      f16x8 b0 = *(const f16x8*)(tb + rd0);
      f16x8 b1 = *(const f16x8*)(tb + rd1);
      float bias = s_bias[jt * 16 + c];
      f32x4 C0 = {0.f, 0.f, 0.f, 0.f};
      C0 = MFMA16(af00, b0, C0); C0 = MFMA16(af01, b1, C0);
      f32x4 C1 = {0.f, 0.f, 0.f, 0.f};
      C1 = MFMA16(af10, b0, C1); C1 = MFMA16(af11, b1, C1);
      const int i = jt - 16;
#pragma unroll
      for (int r = 0; r < 4; r++) {
        p2[0][r] += s_a1[w][quad * 4 + r][i] * (C0[r] + bias);
        p2[1][r] += s_a1[w][16 + quad * 4 + r][i] * (C1[r] + bias);
      }
    }
  }
#pragma unroll 1
  for (int ch = 6; ch < 8; ch++) {
    __syncthreads();
    stage16(W2Tc + (ch + 1) * 8192 + gofs, ring + ((ch + 1) & 1) * 8192 + lofs);
    stage16(W2Tc + (ch + 1) * 8192 + 4096 + gofs,
            ring + ((ch + 1) & 1) * 8192 + 4096 + lofs);
    const char* bb = ring + (ch & 1) * 8192;
#pragma unroll
    for (int q = 0; q < 4; q++) {
      const int jt = ch * 4 + q;
      const char* tb = bb + q * 2048;
      f16x8 b0 = *(const f16x8*)(tb + rd0);
      f16x8 b1 = *(const f16x8*)(tb + rd1);
      float bias = s_bias[jt * 16 + c];
      f32x4 C0 = {0.f, 0.f, 0.f, 0.f};
      C0 = MFMA16(af00, b0, C0); C0 = MFMA16(af01, b1, C0);
      f32x4 C1 = {0.f, 0.f, 0.f, 0.f};
      C1 = MFMA16(af10, b0, C1); C1 = MFMA16(af11, b1, C1);
      const int i = (jt - 24) * 2 + (c >> 3);
#pragma unroll
      for (int r = 0; r < 4; r++) {
        t3[0][r] += s_sn[w][quad * 4 + r][i] * (C0[r] + bias);
        t3[1][r] += s_sn[w][16 + quad * 4 + r][i] * (C1[r] + bias);
      }
    }
  }
  {  // ch = 8, last chunk, no further staging
    __syncthreads();
    const char* bb = ring + 8192;   // chunk 8 is odd slot
#pragma unroll
    for (int q = 0; q < 4; q++) {
      const int jt = 32 + q;
      const char* tb = bb + q * 2048;
      f16x8 b0 = *(const f16x8*)(tb + rd0);
      f16x8 b1 = *(const f16x8*)(tb + rd1);
      float bias = s_bias[jt * 16 + c];
      f32x4 C0 = {0.f, 0.f, 0.f, 0.f};
      C0 = MFMA16(af00, b0, C0); C0 = MFMA16(af01, b1, C0);
      f32x4 C1 = {0.f, 0.f, 0.f, 0.f};
      C1 = MFMA16(af10, b0, C1); C1 = MFMA16(af11, b1, C1);
      const int i = q * 2 + (c >> 3);
#pragma unroll
      for (int r = 0; r < 4; r++) {
        float wv0 = C0[r] + bias;
        float wv1 = C1[r] + bias;
        mx[0][r] += s_v[w][quad * 4 + r][3 * i] * wv0;
        my[0][r] += s_v[w][quad * 4 + r][3 * i + 1] * wv0;
        mz[0][r] += s_v[w][quad * 4 + r][3 * i + 2] * wv0;
        mx[1][r] += s_v[w][16 + quad * 4 + r][3 * i] * wv1;
        my[1][r] += s_v[w][16 + quad * 4 + r][3 * i + 1] * wv1;
        mz[1][r] += s_v[w][16 + quad * 4 + r][3 * i + 2] * wv1;
      }
    }
  }

  // fold the two column-halves (c and c^8 share output j = c&7; after the
  // fold BOTH lanes hold the identical folded sums)
#pragma unroll
  for (int g = 0; g < 2; g++)
#pragma unroll
    for (int r = 0; r < 4; r++) {
      t3[g][r] += __shfl_xor(t3[g][r], 8);
      mx[g][r] += __shfl_xor(mx[g][r], 8);
      my[g][r] += __shfl_xor(my[g][r], 8);
      mz[g][r] += __shfl_xor(mz[g][r], 8);
    }

  // ---- epilogue: atomic scatter, split across half-waves ----
  // c<8 writes agg0 + (x,y) of column c; c>=8 writes agg0 + (z) of column
  // c-8 (identical folded value); c==8 also writes normb.
#pragma unroll
  for (int g = 0; g < 2; g++) {
    const int e0g = g * 16 + quad * 4;
    int cur = __shfl(dstv, e0g);
    float acc0 = 0.f, a1x = 0.f, a1y = 0.f, a1z = 0.f, nacc = 0.f;
#pragma unroll
    for (int r = 0; r < 4; r++) {
      const int e = e0g + r;
      const int dst = __shfl(dstv, e);
      const float ew = __shfl(ewv, e);
      if (dst != cur) {
        atomicAdd(&agg0[(long long)cur * 16 + c], acc0);
        if (c < 8) {
          long long b = (long long)cur * 24 + (long long)c * 3;
          atomicAdd(&agg1[b], a1x);
          atomicAdd(&agg1[b + 1], a1y);
        } else {
          long long b = (long long)cur * 24 + (long long)(c - 8) * 3;
          atomicAdd(&agg1[b + 2], a1z);
          if (c == 8) atomicAdd(&normb[cur], nacc);
        }
        acc0 = a1x = a1y = a1z = nacc = 0.f;
        cur = dst;
      }
      float sc2 = A_PATH * ew;
      float sh0 = s_sh[w][e][0];
      acc0 += (sh0 * p1[g][r] + p2[g][r]) * sc2;
      float t3v = t3[g][r] * sc2;
      float scs = sc2 * sh0;
      if (c < 8) {
        a1x += t3v * s_sh[w][e][1] + mx[g][r] * scs;
        a1y += t3v * s_sh[w][e][2] + my[g][r] * scs;
      } else {
        a1z += t3v * s_sh[w][e][3] + mz[g][r] * scs;
        if (c == 8) nacc += ew;
      }
    }
    atomicAdd(&agg0[(long long)cur * 16 + c], acc0);
    if (c < 8) {
      long long b = (long long)cur * 24 + (long long)c * 3;
      atomicAdd(&agg1[b], a1x);
      atomicAdd(&agg1[b + 1], a1y);
    } else {
      long long b = (long long)cur * 24 + (long long)(c - 8) * 3;
      atomicAdd(&agg1[b + 2], a1z);
      if (c == 8) atomicAdd(&normb[cur], nacc);
    }
  }
}

// ---------------- final node kernel ----------------
extern "C" __global__ __launch_bounds__(64) void k_node(
    const float* __restrict__ x, const float* __restrict__ xnorm,
    const float* __restrict__ agg0, const float* __restrict__ agg1,
    const float* __restrict__ normb, const float* __restrict__ Wm_s,
    const float* __restrict__ Wm_v, const float* __restrict__ Wu_s,
    const float* __restrict__ Wu_v, const float* __restrict__ Ws_s,
    const float* __restrict__ Ws_v, const float* __restrict__ res_scale_p,
    float* __restrict__ out, int N) {
  __shared__ float sWms[384];
  __shared__ float sWmv[64];
  __shared__ float sWus[256];
  __shared__ float sWuv[64];
  __shared__ float sWss[256];
  __shared__ float sWsv[64];
  int t = threadIdx.x;
  for (int i = t; i < 384; i += 64) sWms[i] = Wm_s[i];
  sWmv[t] = Wm_v[t];
  for (int i = t; i < 256; i += 64) sWus[i] = Wu_s[i];
  sWuv[t] = Wu_v[t];
  for (int i = t; i < 256; i += 64) sWss[i] = Ws_s[i];
  sWsv[t] = Ws_v[t];
  __syncthreads();
  int n = blockIdx.x * 64 + t;
  if (n >= N) return;

  float inv = 1.0f / fmaxf(normb[n], EPSF);
  float4 a04[4], a14[6];
  {
    const float4* p = (const float4*)(agg0 + (long long)n * 16);
#pragma unroll
    for (int i = 0; i < 4; i++) a04[i] = p[i];
    const float4* q = (const float4*)(agg1 + (long long)n * 24);
#pragma unroll
    for (int i = 0; i < 6; i++) a14[i] = q[i];
  }
  float* a0 = (float*)a04;
  float* a1 = (float*)a14;
#pragma unroll
  for (int i = 0; i < 16; i++) a0[i] *= inv;
#pragma unroll
  for (int i = 0; i < 24; i++) a1[i] *= inv;

  float scal[16], gate[8];
#pragma unroll
  for (int jj = 0; jj < 24; jj++) {
    float acc = 0.f;
#pragma unroll
    for (int i = 0; i < 16; i++) acc += a0[i] * sWms[i * 24 + jj];
    acc *= Q16;
    if (jj < 16) scal[jj] = acc * sigm(acc);
    else gate[jj - 16] = sigm(acc);
  }
  float vg[24];
#pragma unroll
  for (int j = 0; j < 8; j++) {
    float g = gate[j];
#pragma unroll
    for (int cc = 0; cc < 3; cc++) {
      float acc = 0.f;
#pragma unroll
      for (int i = 0; i < 8; i++) acc += a1[i * 3 + cc] * sWmv[i * 8 + j];
      vg[j * 3 + cc] = acc * Q8 * g;
    }
  }
  float4 xn4[10], xo4[10];
  {
    const float4* p = (const float4*)(xnorm + (long long)n * 40);
    const float4* q = (const float4*)(x + (long long)n * 40);
#pragma unroll
    for (int i = 0; i < 10; i++) { xn4[i] = p[i]; xo4[i] = q[i]; }
  }
  const float* xn = (const float*)xn4;
  const float* xo = (const float*)xo4;
  float rs = res_scale_p[0];

  float4 ob[10];
  float* ov = (float*)ob;
#pragma unroll
  for (int j = 0; j < 16; j++) {
    float acc = 0.f, acc2 = 0.f;
#pragma unroll
    for (int i = 0; i < 16; i++) {
      acc += scal[i] * sWus[i * 16 + j];
      acc2 += xn[i] * sWss[i * 16 + j];
    }
    ov[j] = xo[j] + rs * ((acc + acc2) * Q16);
  }
#pragma unroll
  for (int j = 0; j < 8; j++) {
#pragma unroll
    for (int cc = 0; cc < 3; cc++) {
      float acc = 0.f;
#pragma unroll
      for (int i = 0; i < 8; i++)
        acc += vg[i * 3 + cc] * sWuv[i * 8 + j] + xn[16 + i * 3 + cc] * sWsv[i * 8 + j];
      ov[16 + j * 3 + cc] = xo[16 + j * 3 + cc] + rs * (acc * Q8);
    }
  }
  float4* po = (float4*)(out + (long long)n * 40);
#pragma unroll
  for (int i = 0; i < 10; i++) po[i] = ob[i];
}

// ---------------- launch: 3 dispatches ----------------
extern "C" void kernel_launch(void* const* d_in, const int* in_sizes, int n_in,
                              void* d_out, int out_size, void* d_ws, size_t ws_size,
                              hipStream_t stream) {
  const float* x = (const float*)d_in[0];
  const int* esrc = (const int*)d_in[1];
  const int* edst = (const int*)d_in[2];
  const float* sh = (const float*)d_in[3];
  const float* rbf = (const float*)d_in[4];
  const float* elen = (const float*)d_in[5];
  const float* w_r1 = (const float*)d_in[6];
  const float* b_r1 = (const float*)d_in[7];
  const float* w_r2 = (const float*)d_in[8];
  const float* b_r2 = (const float*)d_in[9];
  const float* w_g1 = (const float*)d_in[10];
  const float* b_g1 = (const float*)d_in[11];
  const float* w_g2 = (const float*)d_in[12];
  const float* b_g2 = (const float*)d_in[13];
  const float* Wm_s = (const float*)d_in[14];
  const float* Wm_v = (const float*)d_in[15];
  const float* Wu_s = (const float*)d_in[16];
  const float* Wu_v = (const float*)d_in[17];
  const float* Ws_s = (const float*)d_in[18];
  const float* Ws_v = (const float*)d_in[19];
  const float* res_scale = (const float*)d_in[20];

  const int N = in_sizes[0] / 40;
  const int E = in_sizes[1];

  char* ws = (char*)d_ws;
  size_t off = 0;
  float* xnorm = (float*)(ws + off); off += (size_t)N * 40 * sizeof(float);
  off = (off + 255) & ~(size_t)255;
  float* agg0 = (float*)(ws + off); off += (size_t)N * 16 * sizeof(float);
  float* agg1 = (float*)(ws + off); off += (size_t)N * 24 * sizeof(float);
  float* normb = (float*)(ws + off); off += (size_t)N * sizeof(float);
  off = (off + 255) & ~(size_t)255;
  f16* W2T = (f16*)(ws + off); off += (size_t)WNUM * 64 * sizeof(f16);

  const int nbN = (N + 255) / 256;

  k_pre<<<nbN, 256, 0, stream>>>(x, xnorm, agg0, agg1, normb, w_r2, W2T, N);

  int nblk = (E + 127) / 128;
  k_edge<<<nblk, 256, 0, stream>>>(xnorm, esrc, edst, sh, rbf, elen,
                                   w_r1, b_r1, w_g1, b_g1, w_g2, b_g2, b_r2,
                                   W2T, agg0, agg1, normb, E);

  k_node<<<(N + 63) / 64, 64, 0, stream>>>(x, xnorm, agg0, agg1, normb, Wm_s,
                                           Wm_v, Wu_s, Wu_v, Ws_s, Ws_v,
                                           res_scale, (float*)d_out, N);
}

// Round 17
// 327.895 us; speedup vs baseline: 1.9737x; 1.0006x over previous
//
#include <hip/hip_runtime.h>
#include <cstdint>

#define MUL0 16
#define MUL1 8
#define NRBF 8
#define HID 64
#define WNUM 576
#define CUTOFF 5.0f
#define EPSF 1e-8f

#define INV_SQRT3 0.57735026918962576f
#define A_PATH    0.20412414523193154f   /* 1/sqrt(24) */
#define Q16       0.25f                  /* 1/sqrt(16) */
#define Q8        0.35355339059327373f   /* 1/sqrt(8)  */
#define PI_OVER_CUT 0.62831853071795865f /* pi/5 */

typedef _Float16 f16;
typedef _Float16 f16x8 __attribute__((ext_vector_type(8)));
typedef float f32x4 __attribute__((ext_vector_type(4)));

#define MFMA16(a, b, cc) __builtin_amdgcn_mfma_f32_16x16x32_f16(a, b, cc, 0, 0, 0)

__device__ __forceinline__ float sigm(float x) { return 1.0f / (1.0f + __expf(-x)); }

typedef __attribute__((address_space(1))) const unsigned char* gptr_t;
typedef __attribute__((address_space(3))) unsigned char* lptr_t;

// async global->LDS DMA, 16B per lane, no staging registers (m97 pattern).
// LDS dest must be wave-uniform; HW adds lane*16.
__device__ __forceinline__ void stage16(const void* g, void* l) {
  __builtin_amdgcn_global_load_lds((gptr_t)g, (lptr_t)l, 16, 0, 0);
}

// compiler-only ordering fence for WAVE-LOCAL LDS RAW (same-wave DS ops
// execute in pipe order; R1-validated). Not a block barrier.
__device__ __forceinline__ void wavefence() {
  asm volatile("" ::: "memory");
  __builtin_amdgcn_wave_barrier();
  asm volatile("" ::: "memory");
}

// ---------------- fused pre-kernel: W2T transpose + xnorm + agg zero ----
// W2T pre-swizzle: within each 2048B jt-tile (16 rows x 128B), 16B chunk h of
// row c goes to slot h ^ (c&7); staged linearly to LDS, read with same XOR.
extern "C" __global__ __launch_bounds__(256) void k_pre(
    const float* __restrict__ x, float* __restrict__ xnorm,
    float* __restrict__ agg0, float* __restrict__ agg1,
    float* __restrict__ normb, const float* __restrict__ w_r2,
    f16* __restrict__ W2T, int N) {
  int gid = blockIdx.x * 256 + threadIdx.x;

  if (gid < HID * WNUM) {
    int n = gid >> 6, k = gid & 63;
    int jt = n >> 4, cc = n & 15;
    int h = k >> 3, e = k & 7;
    int dst = jt * 1024 + cc * 64 + ((h ^ (cc & 7)) << 3) + e;
    W2T[dst] = (f16)w_r2[k * WNUM + n];
  }

  if (gid < N) {
    long long n = gid;
    const float4* xr = (const float4*)(x + n * 40);
    float4 vv[10];
#pragma unroll
    for (int i = 0; i < 10; i++) vv[i] = xr[i];
    float* f = (float*)vv;
    float ss = 0.f, vs = 0.f;
#pragma unroll
    for (int i = 0; i < 16; i++) ss += f[i] * f[i];
#pragma unroll
    for (int i = 16; i < 40; i++) vs += f[i] * f[i];
    float sr = rsqrtf(ss * (1.0f / 16.0f) + EPSF);
    float vr = rsqrtf(vs * (1.0f / 8.0f) + EPSF);
#pragma unroll
    for (int i = 0; i < 16; i++) f[i] *= sr;
#pragma unroll
    for (int i = 16; i < 40; i++) f[i] *= vr;
    float4* o = (float4*)(xnorm + n * 40);
#pragma unroll
    for (int i = 0; i < 10; i++) o[i] = vv[i];
    float4 z = {0.f, 0.f, 0.f, 0.f};
    float4* pa0 = (float4*)(agg0 + n * 16);
#pragma unroll
    for (int i = 0; i < 4; i++) pa0[i] = z;
    float4* pa1 = (float4*)(agg1 + n * 24);
#pragma unroll
    for (int i = 0; i < 6; i++) pa1[i] = z;
    normb[n] = 0.f;
  }
}

// ---------------- fused edge kernel (R12/R16 structure) ----------
// 4 waves/block, 32 edges/wave. B-phase W2T via double-buffered 2x8KB LDS
// ring staged with global_load_lds DMA (R10/R11: no spills, latency hidden).
// Ring aliases dead s_H; bias aliases dead s_rbf; 9 barrier drains.
// R17: the two A-phase block barriers protect only WAVE-LOCAL LDS -> replaced
// with wavefence (compiler fence). Block syncs/tile 12 -> 10; waves drift
// within A and re-align at the pre-ring barrier (bounded, unlike R1).
extern "C" __global__ __launch_bounds__(256, 3) void k_edge(
    const float* __restrict__ xnorm,
    const int* __restrict__ esrc, const int* __restrict__ edst,
    const float* __restrict__ sh, const float* __restrict__ rbf,
    const float* __restrict__ elen,
    const float* __restrict__ w_r1, const float* __restrict__ b_r1,
    const float* __restrict__ w_g1, const float* __restrict__ b_g1,
    const float* __restrict__ w_g2, const float* __restrict__ b_g2,
    const float* __restrict__ b_r2, const f16* __restrict__ W2T,
    float* __restrict__ agg0, float* __restrict__ agg1,
    float* __restrict__ normb, int E) {
  __shared__ __align__(16) char smem[53248];
  f16   (*s_H)[32][72]  = (f16(*)[32][72])(smem);             // 18432 (dead in B)
  float (*s_sn)[32][20] = (float(*)[32][20])(smem + 18432);   // 10240
  float (*s_v)[32][26]  = (float(*)[32][26])(smem + 28672);   // 13312
  float (*s_a1)[32][10] = (float(*)[32][10])(smem + 41984);   //  5120
  float (*s_sh)[32][4]  = (float(*)[32][4])(smem + 47104);    //  2048
  float (*s_rbf)[32][8] = (float(*)[32][8])(smem + 49152);    //  4096 (dead in B)
  float* s_bias = (float*)(smem + 49152);                     // aliases s_rbf

  const int t = threadIdx.x;
  const int w = t >> 6;
  const int lane = t & 63;
  const long long eb = (long long)blockIdx.x * 128 + w * 32;

  // ---- A0: direct coalesced edge loads (OOB edges -> zeros, ew forced 0) ----
  int dstv = 0, srcv = 0;
  float lenv = 1e9f;
  if (lane < 32) {
    long long g2 = eb + lane;
    float4 shv = {0.f, 0.f, 0.f, 0.f};
    if (g2 < E) {
      srcv = esrc[g2];
      dstv = edst[g2];
      lenv = elen[g2];
      shv = *(const float4*)&sh[g2 * 4];
    }
    *(float4*)&s_sh[w][lane][0] = shv;
  }
  {
    int e = lane >> 1, half = lane & 1;
    long long ge2 = eb + e;
    float4 rv4 = {0.f, 0.f, 0.f, 0.f};
    if (ge2 < E) rv4 = *(const float4*)&rbf[ge2 * 8 + half * 4];
    *(float4*)&s_rbf[w][e][half * 4] = rv4;
  }
  wavefence();   // A0 stores are wave-local; no block barrier needed

  // ---- A1: gather xnorm + transform (4 lanes/edge, 2 groups) ----
  {
    const int ge_l = lane >> 2;
    const int part = lane & 3;
#pragma unroll
    for (int g = 0; g < 2; g++) {
      int e = g * 16 + ge_l;
      int srcn = __shfl(srcv, e);
      const float* xr = xnorm + (long long)srcn * 40;
      if (part < 2) {
        float4 aLo = *(const float4*)(xr + part * 8);
        float4 aHi = *(const float4*)(xr + part * 8 + 4);
        *(float4*)&s_sn[w][e][part * 8] = aLo;
        *(float4*)&s_sn[w][e][part * 8 + 4] = aHi;
      } else {
        const int i0 = (part - 2) * 4;
        const float* vp = xr + 16 + i0 * 3;
        float4 v0 = *(const float4*)(vp);
        float4 v1 = *(const float4*)(vp + 4);
        float4 v2 = *(const float4*)(vp + 8);
        *(float4*)&s_v[w][e][i0 * 3] = v0;
        *(float4*)&s_v[w][e][i0 * 3 + 4] = v1;
        *(float4*)&s_v[w][e][i0 * 3 + 8] = v2;
        float4 shq = *(const float4*)&s_sh[w][e][0];
        float s1x = shq.y, s1y = shq.z, s1z = shq.w;
        s_a1[w][e][i0]     = INV_SQRT3 * (v0.x * s1x + v0.y * s1y + v0.z * s1z);
        s_a1[w][e][i0 + 1] = INV_SQRT3 * (v0.w * s1x + v1.x * s1y + v1.y * s1z);
        s_a1[w][e][i0 + 2] = INV_SQRT3 * (v1.z * s1x + v1.w * s1y + v2.x * s1z);
        s_a1[w][e][i0 + 3] = INV_SQRT3 * (v2.y * s1x + v2.z * s1y + v2.w * s1z);
      }
    }
  }

  // ---- A2: hidden layer H (f16), lane = h, 32 edges ----
  {
    float wr[8];
#pragma unroll
    for (int r = 0; r < 8; r++) wr[r] = w_r1[r * HID + lane];
    float bh = b_r1[lane];
#pragma unroll 4
    for (int u = 0; u < 32; u++) {
      float4 ra = *(const float4*)&s_rbf[w][u][0];
      float4 rb2 = *(const float4*)&s_rbf[w][u][4];
      float acc = bh + ra.x * wr[0] + ra.y * wr[1] + ra.z * wr[2] + ra.w * wr[3]
                     + rb2.x * wr[4] + rb2.y * wr[5] + rb2.z * wr[6] + rb2.w * wr[7];
      s_H[w][u][lane] = (f16)(acc * sigm(acc));
    }
  }

  // ---- A3: gate MLP, 2 lanes/edge x 32 h-units ----
  float ewv = 0.f;
  {
    const int eg = lane & 31;
    const int hf = lane >> 5;
    float4 ga = *(const float4*)&s_rbf[w][eg][0];
    float4 gb = *(const float4*)&s_rbf[w][eg][4];
    float rv[8] = {ga.x, ga.y, ga.z, ga.w, gb.x, gb.y, gb.z, gb.w};
    float accp = 0.f;
#pragma unroll
    for (int ch = 0; ch < 2; ch++) {
      const int base = hf * 32 + ch * 16;
      float ttv[16];
      {
        const float4 b0 = *(const float4*)&b_g1[base];
        const float4 b1 = *(const float4*)&b_g1[base + 4];
        const float4 b2 = *(const float4*)&b_g1[base + 8];
        const float4 b3 = *(const float4*)&b_g1[base + 12];
        ttv[0] = b0.x; ttv[1] = b0.y; ttv[2] = b0.z; ttv[3] = b0.w;
        ttv[4] = b1.x; ttv[5] = b1.y; ttv[6] = b1.z; ttv[7] = b1.w;
        ttv[8] = b2.x; ttv[9] = b2.y; ttv[10] = b2.z; ttv[11] = b2.w;
        ttv[12] = b3.x; ttv[13] = b3.y; ttv[14] = b3.z; ttv[15] = b3.w;
      }
#pragma unroll
      for (int r = 0; r < 8; r++) {
        const float* wg = w_g1 + r * HID + base;
        float4 w0 = *(const float4*)(wg);
        float4 w1 = *(const float4*)(wg + 4);
        float4 w2 = *(const float4*)(wg + 8);
        float4 w3 = *(const float4*)(wg + 12);
        float rr = rv[r];
        ttv[0] += rr * w0.x; ttv[1] += rr * w0.y; ttv[2] += rr * w0.z; ttv[3] += rr * w0.w;
        ttv[4] += rr * w1.x; ttv[5] += rr * w1.y; ttv[6] += rr * w1.z; ttv[7] += rr * w1.w;
        ttv[8] += rr * w2.x; ttv[9] += rr * w2.y; ttv[10] += rr * w2.z; ttv[11] += rr * w2.w;
        ttv[12] += rr * w3.x; ttv[13] += rr * w3.y; ttv[14] += rr * w3.z; ttv[15] += rr * w3.w;
      }
      const float4 g0 = *(const float4*)&w_g2[base];
      const float4 g1 = *(const float4*)&w_g2[base + 4];
      const float4 g2 = *(const float4*)&w_g2[base + 8];
      const float4 g3 = *(const float4*)&w_g2[base + 12];
      float gw[16] = {g0.x, g0.y, g0.z, g0.w, g1.x, g1.y, g1.z, g1.w,
                      g2.x, g2.y, g2.z, g2.w, g3.x, g3.y, g3.z, g3.w};
#pragma unroll
      for (int k = 0; k < 16; k++) accp += ttv[k] * sigm(ttv[k]) * gw[k];
    }
    accp += __shfl_xor(accp, 32);
    if (lane < 32) {
      long long g2e = eb + lane;
      if (g2e < E) {
        float cw = (lenv < CUTOFF) ? 0.5f * (__cosf(PI_OVER_CUT * lenv) + 1.0f) : 0.f;
        ewv = cw * sigm(accp + b_g2[0]);
      }
    }
  }
  wavefence();   // s_H writes are wave-local; af-loads below are same-wave

  // ---- B prologue: af regs + bias to LDS, then free s_H for the ring ----
  const int quad = lane >> 4;
  const int c = lane & 15;

  const f16x8 af00 = *(const f16x8*)&s_H[w][c][quad * 8];
  const f16x8 af01 = *(const f16x8*)&s_H[w][c][32 + quad * 8];
  const f16x8 af10 = *(const f16x8*)&s_H[w][16 + c][quad * 8];
  const f16x8 af11 = *(const f16x8*)&s_H[w][16 + c][32 + quad * 8];
  for (int i = t; i < WNUM; i += 256) s_bias[i] = b_r2[i];
  __syncthreads();   // BLOCK barrier: all waves' af reads done before ring
                     // overwrites s_H; bias visible to all waves

  char* ring = smem;                      // 2 x 8192B buffers
  const char* W2Tc = (const char*)W2T;
  const int lofs = w * 1024;              // wave-uniform LDS segment
  const int gofs = w * 1024 + lane * 16;  // per-lane global offset

  // chunk 0 (8KB = two 4KB halves; each wave stages 1KB per half)
  stage16(W2Tc + gofs, ring + lofs);
  stage16(W2Tc + 4096 + gofs, ring + 4096 + lofs);

  const int rd0 = c * 128 + ((quad ^ (c & 7)) << 4);
  const int rd1 = c * 128 + (((quad + 4) ^ (c & 7)) << 4);

  float p1[2][4] = {{0.f}}, p2[2][4] = {{0.f}}, t3[2][4] = {{0.f}};
  float mx[2][4] = {{0.f}}, my[2][4] = {{0.f}}, mz[2][4] = {{0.f}};

  // 9 chunks of 8KB = 4 jt-tiles each. Class boundaries align to chunks:
  // ch 0..3 -> jt 0..15 (p1), ch 4..5 -> jt 16..23 (p2),
  // ch 6..7 -> jt 24..31 (t3), ch 8 -> jt 32..35 (m*).
#pragma unroll 1
  for (int ch = 0; ch < 4; ch++) {
    __syncthreads();
    stage16(W2Tc + (ch + 1) * 8192 + gofs, ring + ((ch + 1) & 1) * 8192 + lofs);
    stage16(W2Tc + (ch + 1) * 8192 + 4096 + gofs,
            ring + ((ch + 1) & 1) * 8192 + 4096 + lofs);
    const char* bb = ring + (ch & 1) * 8192;
#pragma unroll
    for (int q = 0; q < 4; q++) {
      const int jt = ch * 4 + q;
      const char* tb = bb + q * 2048;
      f16x8 b0 = *(const f16x8*)(tb + rd0);
      f16x8 b1 = *(const f16x8*)(tb + rd1);
      float bias = s_bias[jt * 16 + c];
      f32x4 C0 = {0.f, 0.f, 0.f, 0.f};
      C0 = MFMA16(af00, b0, C0); C0 = MFMA16(af01, b1, C0);
      f32x4 C1 = {0.f, 0.f, 0.f, 0.f};
      C1 = MFMA16(af10, b0, C1); C1 = MFMA16(af11, b1, C1);
#pragma unroll
      for (int r = 0; r < 4; r++) {
        p1[0][r] += s_sn[w][quad * 4 + r][jt] * (C0[r] + bias);
        p1[1][r] += s_sn[w][16 + quad * 4 + r][jt] * (C1[r] + bias);
      }
    }
  }
#pragma unroll 1
  for (int ch = 4; ch < 6; ch++) {
    __syncthreads();
    stage16(W2Tc + (ch + 1) * 8192 + gofs, ring + ((ch + 1) & 1) * 8192 + lofs);
    stage16(W2Tc + (ch + 1) * 8192 + 4096 + gofs,
            ring + ((ch + 1) & 1) * 8192 + 4096 + lofs);
    const char* bb = ring + (ch & 1) * 8192;
#pragma unroll
    for (int q = 0; q < 4; q++) {
      const int jt = ch * 4 + q;
      const char* tb = bb + q * 2048;
      f16x8 b0 = *(const f16x8*)(tb + rd0);
      f16x8 b1 = *(const f16x8*)(tb + rd1);
      float bias = s_bias[jt * 16 + c];
      f32x4 C0 = {0.f, 0.f, 0.f, 0.f};
      C0 = MFMA16(af00, b0, C0); C0 = MFMA16(af01, b1, C0);
      f32x4 C1 = {0.f, 0.f, 0.f, 0.f};
      C1 = MFMA16(af10, b0, C1); C1 = MFMA16(af11, b1, C1);
      const int i = jt - 16;
#pragma unroll
      for (int r = 0; r < 4; r++) {
        p2[0][r] += s_a1[w][quad * 4 + r][i] * (C0[r] + bias);
        p2[1][r] += s_a1[w][16 + quad * 4 + r][i] * (C1[r] + bias);
      }
    }
  }
#pragma unroll 1
  for (int ch = 6; ch < 8; ch++) {
    __syncthreads();
    stage16(W2Tc + (ch + 1) * 8192 + gofs, ring + ((ch + 1) & 1) * 8192 + lofs);
    stage16(W2Tc + (ch + 1) * 8192 + 4096 + gofs,
            ring + ((ch + 1) & 1) * 8192 + 4096 + lofs);
    const char* bb = ring + (ch & 1) * 8192;
#pragma unroll
    for (int q = 0; q < 4; q++) {
      const int jt = ch * 4 + q;
      const char* tb = bb + q * 2048;
      f16x8 b0 = *(const f16x8*)(tb + rd0);
      f16x8 b1 = *(const f16x8*)(tb + rd1);
      float bias = s_bias[jt * 16 + c];
      f32x4 C0 = {0.f, 0.f, 0.f, 0.f};
      C0 = MFMA16(af00, b0, C0); C0 = MFMA16(af01, b1, C0);
      f32x4 C1 = {0.f, 0.f, 0.f, 0.f};
      C1 = MFMA16(af10, b0, C1); C1 = MFMA16(af11, b1, C1);
      const int i = (jt - 24) * 2 + (c >> 3);
#pragma unroll
      for (int r = 0; r < 4; r++) {
        t3[0][r] += s_sn[w][quad * 4 + r][i] * (C0[r] + bias);
        t3[1][r] += s_sn[w][16 + quad * 4 + r][i] * (C1[r] + bias);
      }
    }
  }
  {  // ch = 8, last chunk, no further staging
    __syncthreads();
    const char* bb = ring + 8192;   // chunk 8 is odd slot
#pragma unroll
    for (int q = 0; q < 4; q++) {
      const int jt = 32 + q;
      const char* tb = bb + q * 2048;
      f16x8 b0 = *(const f16x8*)(tb + rd0);
      f16x8 b1 = *(const f16x8*)(tb + rd1);
      float bias = s_bias[jt * 16 + c];
      f32x4 C0 = {0.f, 0.f, 0.f, 0.f};
      C0 = MFMA16(af00, b0, C0); C0 = MFMA16(af01, b1, C0);
      f32x4 C1 = {0.f, 0.f, 0.f, 0.f};
      C1 = MFMA16(af10, b0, C1); C1 = MFMA16(af11, b1, C1);
      const int i = q * 2 + (c >> 3);
#pragma unroll
      for (int r = 0; r < 4; r++) {
        float wv0 = C0[r] + bias;
        float wv1 = C1[r] + bias;
        mx[0][r] += s_v[w][quad * 4 + r][3 * i] * wv0;
        my[0][r] += s_v[w][quad * 4 + r][3 * i + 1] * wv0;
        mz[0][r] += s_v[w][quad * 4 + r][3 * i + 2] * wv0;
        mx[1][r] += s_v[w][16 + quad * 4 + r][3 * i] * wv1;
        my[1][r] += s_v[w][16 + quad * 4 + r][3 * i + 1] * wv1;
        mz[1][r] += s_v[w][16 + quad * 4 + r][3 * i + 2] * wv1;
      }
    }
  }

  // fold the two column-halves (c and c^8 share output j = c&7; after the
  // fold BOTH lanes hold the identical folded sums)
#pragma unroll
  for (int g = 0; g < 2; g++)
#pragma unroll
    for (int r = 0; r < 4; r++) {
      t3[g][r] += __shfl_xor(t3[g][r], 8);
      mx[g][r] += __shfl_xor(mx[g][r], 8);
      my[g][r] += __shfl_xor(my[g][r], 8);
      mz[g][r] += __shfl_xor(mz[g][r], 8);
    }

  // ---- epilogue: atomic scatter, split across half-waves (R16-verified) ----
#pragma unroll
  for (int g = 0; g < 2; g++) {
    const int e0g = g * 16 + quad * 4;
    int cur = __shfl(dstv, e0g);
    float acc0 = 0.f, a1x = 0.f, a1y = 0.f, a1z = 0.f, nacc = 0.f;
#pragma unroll
    for (int r = 0; r < 4; r++) {
      const int e = e0g + r;
      const int dst = __shfl(dstv, e);
      const float ew = __shfl(ewv, e);
      if (dst != cur) {
        atomicAdd(&agg0[(long long)cur * 16 + c], acc0);
        if (c < 8) {
          long long b = (long long)cur * 24 + (long long)c * 3;
          atomicAdd(&agg1[b], a1x);
          atomicAdd(&agg1[b + 1], a1y);
        } else {
          long long b = (long long)cur * 24 + (long long)(c - 8) * 3;
          atomicAdd(&agg1[b + 2], a1z);
          if (c == 8) atomicAdd(&normb[cur], nacc);
        }
        acc0 = a1x = a1y = a1z = nacc = 0.f;
        cur = dst;
      }
      float sc2 = A_PATH * ew;
      float sh0 = s_sh[w][e][0];
      acc0 += (sh0 * p1[g][r] + p2[g][r]) * sc2;
      float t3v = t3[g][r] * sc2;
      float scs = sc2 * sh0;
      if (c < 8) {
        a1x += t3v * s_sh[w][e][1] + mx[g][r] * scs;
        a1y += t3v * s_sh[w][e][2] + my[g][r] * scs;
      } else {
        a1z += t3v * s_sh[w][e][3] + mz[g][r] * scs;
        if (c == 8) nacc += ew;
      }
    }
    atomicAdd(&agg0[(long long)cur * 16 + c], acc0);
    if (c < 8) {
      long long b = (long long)cur * 24 + (long long)c * 3;
      atomicAdd(&agg1[b], a1x);
      atomicAdd(&agg1[b + 1], a1y);
    } else {
      long long b = (long long)cur * 24 + (long long)(c - 8) * 3;
      atomicAdd(&agg1[b + 2], a1z);
      if (c == 8) atomicAdd(&normb[cur], nacc);
    }
  }
}

// ---------------- final node kernel ----------------
extern "C" __global__ __launch_bounds__(64) void k_node(
    const float* __restrict__ x, const float* __restrict__ xnorm,
    const float* __restrict__ agg0, const float* __restrict__ agg1,
    const float* __restrict__ normb, const float* __restrict__ Wm_s,
    const float* __restrict__ Wm_v, const float* __restrict__ Wu_s,
    const float* __restrict__ Wu_v, const float* __restrict__ Ws_s,
    const float* __restrict__ Ws_v, const float* __restrict__ res_scale_p,
    float* __restrict__ out, int N) {
  __shared__ float sWms[384];
  __shared__ float sWmv[64];
  __shared__ float sWus[256];
  __shared__ float sWuv[64];
  __shared__ float sWss[256];
  __shared__ float sWsv[64];
  int t = threadIdx.x;
  for (int i = t; i < 384; i += 64) sWms[i] = Wm_s[i];
  sWmv[t] = Wm_v[t];
  for (int i = t; i < 256; i += 64) sWus[i] = Wu_s[i];
  sWuv[t] = Wu_v[t];
  for (int i = t; i < 256; i += 64) sWss[i] = Ws_s[i];
  sWsv[t] = Ws_v[t];
  __syncthreads();
  int n = blockIdx.x * 64 + t;
  if (n >= N) return;

  float inv = 1.0f / fmaxf(normb[n], EPSF);
  float4 a04[4], a14[6];
  {
    const float4* p = (const float4*)(agg0 + (long long)n * 16);
#pragma unroll
    for (int i = 0; i < 4; i++) a04[i] = p[i];
    const float4* q = (const float4*)(agg1 + (long long)n * 24);
#pragma unroll
    for (int i = 0; i < 6; i++) a14[i] = q[i];
  }
  float* a0 = (float*)a04;
  float* a1 = (float*)a14;
#pragma unroll
  for (int i = 0; i < 16; i++) a0[i] *= inv;
#pragma unroll
  for (int i = 0; i < 24; i++) a1[i] *= inv;

  float scal[16], gate[8];
#pragma unroll
  for (int jj = 0; jj < 24; jj++) {
    float acc = 0.f;
#pragma unroll
    for (int i = 0; i < 16; i++) acc += a0[i] * sWms[i * 24 + jj];
    acc *= Q16;
    if (jj < 16) scal[jj] = acc * sigm(acc);
    else gate[jj - 16] = sigm(acc);
  }
  float vg[24];
#pragma unroll
  for (int j = 0; j < 8; j++) {
    float g = gate[j];
#pragma unroll
    for (int cc = 0; cc < 3; cc++) {
      float acc = 0.f;
#pragma unroll
      for (int i = 0; i < 8; i++) acc += a1[i * 3 + cc] * sWmv[i * 8 + j];
      vg[j * 3 + cc] = acc * Q8 * g;
    }
  }
  float4 xn4[10], xo4[10];
  {
    const float4* p = (const float4*)(xnorm + (long long)n * 40);
    const float4* q = (const float4*)(x + (long long)n * 40);
#pragma unroll
    for (int i = 0; i < 10; i++) { xn4[i] = p[i]; xo4[i] = q[i]; }
  }
  const float* xn = (const float*)xn4;
  const float* xo = (const float*)xo4;
  float rs = res_scale_p[0];

  float4 ob[10];
  float* ov = (float*)ob;
#pragma unroll
  for (int j = 0; j < 16; j++) {
    float acc = 0.f, acc2 = 0.f;
#pragma unroll
    for (int i = 0; i < 16; i++) {
      acc += scal[i] * sWus[i * 16 + j];
      acc2 += xn[i] * sWss[i * 16 + j];
    }
    ov[j] = xo[j] + rs * ((acc + acc2) * Q16);
  }
#pragma unroll
  for (int j = 0; j < 8; j++) {
#pragma unroll
    for (int cc = 0; cc < 3; cc++) {
      float acc = 0.f;
#pragma unroll
      for (int i = 0; i < 8; i++)
        acc += vg[i * 3 + cc] * sWuv[i * 8 + j] + xn[16 + i * 3 + cc] * sWsv[i * 8 + j];
      ov[16 + j * 3 + cc] = xo[16 + j * 3 + cc] + rs * (acc * Q8);
    }
  }
  float4* po = (float4*)(out + (long long)n * 40);
#pragma unroll
  for (int i = 0; i < 10; i++) po[i] = ob[i];
}

// ---------------- launch: 3 dispatches ----------------
extern "C" void kernel_launch(void* const* d_in, const int* in_sizes, int n_in,
                              void* d_out, int out_size, void* d_ws, size_t ws_size,
                              hipStream_t stream) {
  const float* x = (const float*)d_in[0];
  const int* esrc = (const int*)d_in[1];
  const int* edst = (const int*)d_in[2];
  const float* sh = (const float*)d_in[3];
  const float* rbf = (const float*)d_in[4];
  const float* elen = (const float*)d_in[5];
  const float* w_r1 = (const float*)d_in[6];
  const float* b_r1 = (const float*)d_in[7];
  const float* w_r2 = (const float*)d_in[8];
  const float* b_r2 = (const float*)d_in[9];
  const float* w_g1 = (const float*)d_in[10];
  const float* b_g1 = (const float*)d_in[11];
  const float* w_g2 = (const float*)d_in[12];
  const float* b_g2 = (const float*)d_in[13];
  const float* Wm_s = (const float*)d_in[14];
  const float* Wm_v = (const float*)d_in[15];
  const float* Wu_s = (const float*)d_in[16];
  const float* Wu_v = (const float*)d_in[17];
  const float* Ws_s = (const float*)d_in[18];
  const float* Ws_v = (const float*)d_in[19];
  const float* res_scale = (const float*)d_in[20];

  const int N = in_sizes[0] / 40;
  const int E = in_sizes[1];

  char* ws = (char*)d_ws;
  size_t off = 0;
  float* xnorm = (float*)(ws + off); off += (size_t)N * 40 * sizeof(float);
  off = (off + 255) & ~(size_t)255;
  float* agg0 = (float*)(ws + off); off += (size_t)N * 16 * sizeof(float);
  float* agg1 = (float*)(ws + off); off += (size_t)N * 24 * sizeof(float);
  float* normb = (float*)(ws + off); off += (size_t)N * sizeof(float);
  off = (off + 255) & ~(size_t)255;
  f16* W2T = (f16*)(ws + off); off += (size_t)WNUM * 64 * sizeof(f16);

  const int nbN = (N + 255) / 256;

  k_pre<<<nbN, 256, 0, stream>>>(x, xnorm, agg0, agg1, normb, w_r2, W2T, N);

  int nblk = (E + 127) / 128;
  k_edge<<<nblk, 256, 0, stream>>>(xnorm, esrc, edst, sh, rbf, elen,
                                   w_r1, b_r1, w_g1, b_g1, w_g2, b_g2, b_r2,
                                   W2T, agg0, agg1, normb, E);

  k_node<<<(N + 63) / 64, 64, 0, stream>>>(x, xnorm, agg0, agg1, normb, Wm_s,
                                           Wm_v, Wu_s, Wu_v, Ws_s, Ws_v,
                                           res_scale, (float*)d_out, N);
}